// Round 1
// baseline (2662.125 us; speedup 1.0000x reference)
//
#include <hip/hip_runtime.h>
#include <hip/hip_bf16.h>
#include <math.h>

#define LR_SLOPE 0.2f

// ---------- helpers: order-preserving float<->uint for atomicMax ----------
__device__ __forceinline__ unsigned f2ord(float f) {
    unsigned u = __float_as_uint(f);
    return (u & 0x80000000u) ? ~u : (u | 0x80000000u);
}
__device__ __forceinline__ float ord2f(unsigned u) {
    unsigned v = (u & 0x80000000u) ? (u ^ 0x80000000u) : ~u;
    return __uint_as_float(v);
}

// ---------- generic tiled GEMM: out = act(A[M,K] @ W[K,N] + bias[N]) ----------
// 64x64 tile, 256 threads, 4x4 per-thread micro tile, K tiled by 16.
__global__ __launch_bounds__(256) void gemm_bias_act(
    const float* __restrict__ A, const float* __restrict__ W,
    const float* __restrict__ bias, float* __restrict__ out,
    int M, int N, int K, int do_relu)
{
    __shared__ float As[16][64];   // [k][m]
    __shared__ float Ws[16][64];   // [k][n]
    const int tid = threadIdx.x;
    const int tx = tid & 15;       // n-dim
    const int ty = tid >> 4;       // m-dim
    const int row0 = blockIdx.x * 64;
    const int col0 = blockIdx.y * 64;

    float acc[4][4] = {{0.f}};

    for (int kk = 0; kk < K; kk += 16) {
        // A tile: thread loads float4 A[row0 + tid/4][kk + (tid%4)*4 ..]
        {
            const int ra = tid >> 2;
            const int ka = (tid & 3) << 2;
            float4 v = make_float4(0.f, 0.f, 0.f, 0.f);
            const int r = row0 + ra;
            if (r < M)
                v = *reinterpret_cast<const float4*>(&A[(size_t)r * K + kk + ka]);
            As[ka + 0][ra] = v.x;
            As[ka + 1][ra] = v.y;
            As[ka + 2][ra] = v.z;
            As[ka + 3][ra] = v.w;
        }
        // W tile: thread loads float4 W[kk + tid/16][col0 + (tid%16)*4 ..]
        {
            const int rw = tid >> 4;
            const int cw = (tid & 15) << 2;
            float4 v = *reinterpret_cast<const float4*>(
                &W[(size_t)(kk + rw) * N + col0 + cw]);
            *reinterpret_cast<float4*>(&Ws[rw][cw]) = v;
        }
        __syncthreads();
#pragma unroll
        for (int k = 0; k < 16; ++k) {
            const float4 a = *reinterpret_cast<const float4*>(&As[k][ty * 4]);
            const float4 b = *reinterpret_cast<const float4*>(&Ws[k][tx * 4]);
            const float av[4] = {a.x, a.y, a.z, a.w};
            const float bv[4] = {b.x, b.y, b.z, b.w};
#pragma unroll
            for (int i = 0; i < 4; ++i)
#pragma unroll
                for (int j = 0; j < 4; ++j)
                    acc[i][j] += av[i] * bv[j];
        }
        __syncthreads();
    }

#pragma unroll
    for (int i = 0; i < 4; ++i) {
        const int r = row0 + ty * 4 + i;
        if (r >= M) continue;
#pragma unroll
        for (int j = 0; j < 4; ++j) {
            const int c = col0 + tx * 4 + j;
            float v = acc[i][j] + bias[c];
            if (do_relu) v = fmaxf(v, 0.f);
            out[(size_t)r * N + c] = v;
        }
    }
}

// ---------- edge kernel A: alpha[e,h] + segment max (wave per edge) ----------
// HC = 256 fixed. H=4 (C=64) or H=1 (C=256).
template <int H>
__global__ __launch_bounds__(256) void edge_alpha_k(
    const float* __restrict__ xl, const float* __restrict__ xr,
    const float* __restrict__ eattr, const float* __restrict__ We,
    const float* __restrict__ att,
    const int* __restrict__ src, const int* __restrict__ dst,
    float* __restrict__ alpha, unsigned* __restrict__ amax, int E)
{
    __shared__ float sWe[8 * 256];
    __shared__ float sAtt[256];
    for (int i = threadIdx.x; i < 8 * 256; i += 256) sWe[i] = We[i];
    sAtt[threadIdx.x] = att[threadIdx.x];
    __syncthreads();

    const int lane = threadIdx.x & 63;
    const int wv = threadIdx.x >> 6;
    const int e = blockIdx.x * 4 + wv;
    if (e >= E) return;

    const int s = src[e];
    const int d = dst[e];

    float ea[8];
#pragma unroll
    for (int t = 0; t < 8; ++t) ea[t] = eattr[(size_t)e * 8 + t];

    float part[4];
#pragma unroll
    for (int j = 0; j < 4; ++j) {
        const int hc = j * 64 + lane;
        float v = xl[(size_t)s * 256 + hc] + xr[(size_t)d * 256 + hc];
#pragma unroll
        for (int t = 0; t < 8; ++t) v += ea[t] * sWe[t * 256 + hc];
        v = (v > 0.f) ? v : LR_SLOPE * v;
        part[j] = v * sAtt[hc];
    }
    // butterfly reduce across the 64-lane wave (all 4 partials)
#pragma unroll
    for (int off = 1; off < 64; off <<= 1) {
#pragma unroll
        for (int j = 0; j < 4; ++j)
            part[j] += __shfl_xor(part[j], off, 64);
    }
    if (lane == 0) {
        if (H == 4) {
#pragma unroll
            for (int h = 0; h < 4; ++h) {
                alpha[(size_t)e * 4 + h] = part[h];
                atomicMax(&amax[(size_t)d * 4 + h], f2ord(part[h]));
            }
        } else {
            const float a0 = part[0] + part[1] + part[2] + part[3];
            alpha[e] = a0;
            atomicMax(&amax[d], f2ord(a0));
        }
    }
}

// ---------- edge kernel B: ex = exp(alpha - amax[dst]); denom += ex ----------
template <int H>
__global__ void edge_exp_k(const float* __restrict__ alpha,
                           const unsigned* __restrict__ amax,
                           const int* __restrict__ dst,
                           float* __restrict__ exv, float* __restrict__ denom,
                           int E)
{
    const int e = blockIdx.x * blockDim.x + threadIdx.x;
    if (e >= E) return;
    const int d = dst[e];
#pragma unroll
    for (int h = 0; h < H; ++h) {
        const float m = ord2f(amax[(size_t)d * H + h]);
        const float x = __expf(alpha[(size_t)e * H + h] - m);
        exv[(size_t)e * H + h] = x;
        atomicAdd(&denom[(size_t)d * H + h], x);
    }
}

// ---------- edge kernel C: out[dst] += xl[src] * a  (wave per edge) ----------
template <int H>
__global__ __launch_bounds__(256) void edge_agg_k(
    const float* __restrict__ xl, const float* __restrict__ exv,
    const float* __restrict__ denom,
    const int* __restrict__ src, const int* __restrict__ dst,
    float* __restrict__ out, int E)
{
    const int lane = threadIdx.x & 63;
    const int wv = threadIdx.x >> 6;
    const int e = blockIdx.x * 4 + wv;
    if (e >= E) return;

    const int s = src[e];
    const int d = dst[e];

    float a[4];
    if (H == 4) {
#pragma unroll
        for (int h = 0; h < 4; ++h)
            a[h] = exv[(size_t)e * 4 + h] / denom[(size_t)d * 4 + h];
    } else {
        const float a0 = exv[e] / denom[d];
        a[0] = a[1] = a[2] = a[3] = a0;
    }
#pragma unroll
    for (int j = 0; j < 4; ++j) {
        const int hc = j * 64 + lane;
        atomicAdd(&out[(size_t)d * 256 + hc],
                  xl[(size_t)s * 256 + hc] * a[j]);
    }
}

// ---------- elementwise: io = relu(io + bias[i % 256]) ----------
__global__ void bias_relu_k(float* __restrict__ io,
                            const float* __restrict__ bias, int total)
{
    const int i = blockIdx.x * blockDim.x + threadIdx.x;
    if (i < total) {
        const float v = io[i] + bias[i & 255];
        io[i] = fmaxf(v, 0.f);
    }
}

extern "C" void kernel_launch(void* const* d_in, const int* in_sizes, int n_in,
                              void* d_out, int out_size, void* d_ws, size_t ws_size,
                              hipStream_t stream)
{
    const float* x     = (const float*)d_in[0];
    const int*   eidx  = (const int*)d_in[1];
    const float* eattr = (const float*)d_in[2];
    const float* W1  = (const float*)d_in[3];
    const float* b1  = (const float*)d_in[4];
    const float* W2  = (const float*)d_in[5];
    const float* b2  = (const float*)d_in[6];
    const float* Wl1 = (const float*)d_in[7];
    const float* bl1 = (const float*)d_in[8];
    const float* Wr1 = (const float*)d_in[9];
    const float* br1 = (const float*)d_in[10];
    const float* We1 = (const float*)d_in[11];
    const float* att1 = (const float*)d_in[12];
    const float* bias1 = (const float*)d_in[13];
    const float* Wl2 = (const float*)d_in[14];
    const float* bl2 = (const float*)d_in[15];
    const float* Wr2 = (const float*)d_in[16];
    const float* br2 = (const float*)d_in[17];
    const float* We2 = (const float*)d_in[18];
    const float* att2 = (const float*)d_in[19];
    const float* bias2 = (const float*)d_in[20];

    const int N = in_sizes[0] / 32;        // 50000
    const int E = in_sizes[2] / 8;         // 800000
    const int* src = eidx;
    const int* dst = eidx + E;

    // ---- workspace layout (bytes, 256-aligned) ----
    auto align256 = [](size_t v) { return (v + 255) & ~(size_t)255; };
    char* ws = (char*)d_ws;
    size_t off = 0;
    float* h1 = (float*)(ws + off);   off += align256((size_t)N * 64 * 4);
    float* h2 = (float*)(ws + off);   off += align256((size_t)N * 64 * 4);
    float* xl = (float*)(ws + off);   off += align256((size_t)N * 256 * 4);
    float* xr = (float*)(ws + off);   off += align256((size_t)N * 256 * 4);
    float* alpha = (float*)(ws + off); off += align256((size_t)E * 4 * 4);
    unsigned* amax = (unsigned*)(ws + off); off += align256((size_t)N * 4 * 4);
    float* denom = (float*)(ws + off); off += align256((size_t)N * 4 * 4);
    float* out1 = (float*)(ws + off);  off += align256((size_t)N * 256 * 4);
    (void)ws_size;

    float* outf = (float*)d_out;

    auto gemm = [&](const float* A, const float* W, const float* bias,
                    float* out, int M, int Nc, int K, int relu) {
        dim3 grid((M + 63) / 64, Nc / 64);
        gemm_bias_act<<<grid, 256, 0, stream>>>(A, W, bias, out, M, Nc, K, relu);
    };

    const int egrid4 = (E + 3) / 4;       // wave-per-edge kernels
    const int egrid1 = (E + 255) / 256;   // thread-per-edge kernels
    const int ngrid = (N * 256 + 255) / 256;

    // ---- MLP encoder ----
    gemm(x,  W1, b1, h1, N, 64, 32, 1);
    gemm(h1, W2, b2, h2, N, 64, 64, 1);

    // ---- GAT layer 1 (H=4, C=64) ----
    gemm(h2, Wl1, bl1, xl, N, 256, 64, 0);
    gemm(h2, Wr1, br1, xr, N, 256, 64, 0);
    hipMemsetAsync(amax, 0, (size_t)N * 4 * 4, stream);
    hipMemsetAsync(denom, 0, (size_t)N * 4 * 4, stream);
    hipMemsetAsync(out1, 0, (size_t)N * 256 * 4, stream);
    edge_alpha_k<4><<<egrid4, 256, 0, stream>>>(xl, xr, eattr, We1, att1,
                                                src, dst, alpha, amax, E);
    edge_exp_k<4><<<egrid1, 256, 0, stream>>>(alpha, amax, dst, alpha, denom, E);
    edge_agg_k<4><<<egrid4, 256, 0, stream>>>(xl, alpha, denom, src, dst, out1, E);
    bias_relu_k<<<ngrid, 256, 0, stream>>>(out1, bias1, N * 256);  // out1 -> h3

    // ---- GAT layer 2 (H=1, C=256) ----
    gemm(out1, Wl2, bl2, xl, N, 256, 256, 0);
    gemm(out1, Wr2, br2, xr, N, 256, 256, 0);
    hipMemsetAsync(amax, 0, (size_t)N * 4, stream);
    hipMemsetAsync(denom, 0, (size_t)N * 4, stream);
    hipMemsetAsync(outf, 0, (size_t)N * 256 * 4, stream);
    edge_alpha_k<1><<<egrid4, 256, 0, stream>>>(xl, xr, eattr, We2, att2,
                                                src, dst, alpha, amax, E);
    edge_exp_k<1><<<egrid1, 256, 0, stream>>>(alpha, amax, dst, alpha, denom, E);
    edge_agg_k<1><<<egrid4, 256, 0, stream>>>(xl, alpha, denom, src, dst, outf, E);
    bias_relu_k<<<ngrid, 256, 0, stream>>>(outf, bias2, N * 256);
}

// Round 2
// 1032.331 us; speedup vs baseline: 2.5788x; 2.5788x over previous
//
#include <hip/hip_runtime.h>
#include <hip/hip_bf16.h>
#include <math.h>

#define LR_SLOPE 0.2f

// ---------- generic tiled GEMM: out = act(A[M,K] @ W[K,N] + bias[N]) ----------
// 64x64 tile, 256 threads, 4x4 per-thread micro tile, K tiled by 16.
__global__ __launch_bounds__(256) void gemm_bias_act(
    const float* __restrict__ A, const float* __restrict__ W,
    const float* __restrict__ bias, float* __restrict__ out,
    int M, int N, int K, int do_relu)
{
    __shared__ float As[16][64];   // [k][m]
    __shared__ float Ws[16][64];   // [k][n]
    const int tid = threadIdx.x;
    const int tx = tid & 15;       // n-dim
    const int ty = tid >> 4;       // m-dim
    const int row0 = blockIdx.x * 64;
    const int col0 = blockIdx.y * 64;

    float acc[4][4] = {{0.f}};

    for (int kk = 0; kk < K; kk += 16) {
        {
            const int ra = tid >> 2;
            const int ka = (tid & 3) << 2;
            float4 v = make_float4(0.f, 0.f, 0.f, 0.f);
            const int r = row0 + ra;
            if (r < M)
                v = *reinterpret_cast<const float4*>(&A[(size_t)r * K + kk + ka]);
            As[ka + 0][ra] = v.x;
            As[ka + 1][ra] = v.y;
            As[ka + 2][ra] = v.z;
            As[ka + 3][ra] = v.w;
        }
        {
            const int rw = tid >> 4;
            const int cw = (tid & 15) << 2;
            float4 v = *reinterpret_cast<const float4*>(
                &W[(size_t)(kk + rw) * N + col0 + cw]);
            *reinterpret_cast<float4*>(&Ws[rw][cw]) = v;
        }
        __syncthreads();
#pragma unroll
        for (int k = 0; k < 16; ++k) {
            const float4 a = *reinterpret_cast<const float4*>(&As[k][ty * 4]);
            const float4 b = *reinterpret_cast<const float4*>(&Ws[k][tx * 4]);
            const float av[4] = {a.x, a.y, a.z, a.w};
            const float bv[4] = {b.x, b.y, b.z, b.w};
#pragma unroll
            for (int i = 0; i < 4; ++i)
#pragma unroll
                for (int j = 0; j < 4; ++j)
                    acc[i][j] += av[i] * bv[j];
        }
        __syncthreads();
    }

#pragma unroll
    for (int i = 0; i < 4; ++i) {
        const int r = row0 + ty * 4 + i;
        if (r >= M) continue;
#pragma unroll
        for (int j = 0; j < 4; ++j) {
            const int c = col0 + tx * 4 + j;
            float v = acc[i][j] + bias[c];
            if (do_relu) v = fmaxf(v, 0.f);
            out[(size_t)r * N + c] = v;
        }
    }
}

// ---------- CSR build ----------
__global__ void hist_k(const int* __restrict__ dst, int* __restrict__ deg, int E)
{
    const int e = blockIdx.x * blockDim.x + threadIdx.x;
    if (e < E) atomicAdd(&deg[dst[e]], 1);
}

// single-block exclusive scan over N entries -> rowptr[0..N], cursor copy
__global__ __launch_bounds__(1024) void exscan_k(
    const int* __restrict__ deg, int* __restrict__ rowptr,
    int* __restrict__ cursor, int N)
{
    __shared__ int buf[1024];
    __shared__ int carry_s;
    if (threadIdx.x == 0) carry_s = 0;
    __syncthreads();
    for (int base = 0; base < N; base += 1024) {
        const int i = base + (int)threadIdx.x;
        const int v = (i < N) ? deg[i] : 0;
        buf[threadIdx.x] = v;
        __syncthreads();
        for (int off = 1; off < 1024; off <<= 1) {
            int t = (threadIdx.x >= (unsigned)off) ? buf[threadIdx.x - off] : 0;
            __syncthreads();
            buf[threadIdx.x] += t;
            __syncthreads();
        }
        const int incl = buf[threadIdx.x];
        const int excl = incl - v;
        const int carry = carry_s;
        if (i < N) { rowptr[i] = carry + excl; cursor[i] = carry + excl; }
        __syncthreads();
        if (threadIdx.x == 1023) carry_s = carry + incl;
        __syncthreads();
    }
    if (threadIdx.x == 0) rowptr[N] = carry_s;
}

// scatter (edge, src) pairs into dst-sorted order
__global__ void scatter_k(const int* __restrict__ src, const int* __restrict__ dst,
                          int* __restrict__ cursor, int2* __restrict__ eord, int E)
{
    const int e = blockIdx.x * blockDim.x + threadIdx.x;
    if (e >= E) return;
    const int d = dst[e];
    const int p = atomicAdd(&cursor[d], 1);
    eord[p] = make_int2(e, src[e]);
}

// ---------- fused node-centric GATv2: score + online softmax + aggregate ----------
// One wave per dst node. HC = 256. H=4 (C=64) or H=1 (C=256).
template <int H>
__global__ __launch_bounds__(256) void node_gat_k(
    const float* __restrict__ xl, const float* __restrict__ xr,
    const float* __restrict__ eattr, const float* __restrict__ We,
    const float* __restrict__ att, const float* __restrict__ bias,
    const int* __restrict__ rowptr, const int2* __restrict__ eord,
    float* __restrict__ out, int N)
{
    __shared__ float sWe[8 * 256];
    __shared__ float sAtt[256];
    __shared__ float sBias[256];
    for (int i = threadIdx.x; i < 8 * 256; i += 256) sWe[i] = We[i];
    sAtt[threadIdx.x] = att[threadIdx.x];
    sBias[threadIdx.x] = bias[threadIdx.x];
    __syncthreads();

    const int lane = threadIdx.x & 63;
    const int n = blockIdx.x * 4 + (threadIdx.x >> 6);
    if (n >= N) return;

    float xrr[4], acc[4] = {0.f, 0.f, 0.f, 0.f};
    float m[4], den[4];
#pragma unroll
    for (int j = 0; j < 4; ++j) {
        xrr[j] = xr[(size_t)n * 256 + j * 64 + lane];
        m[j] = -INFINITY;
        den[j] = 0.f;
    }

    const int k0 = rowptr[n], k1 = rowptr[n + 1];
    for (int k = k0; k < k1; ++k) {
        const int2 es = eord[k];
        const float* xlrow = &xl[(size_t)es.y * 256];
        float ea[8];
#pragma unroll
        for (int t = 0; t < 8; ++t) ea[t] = eattr[(size_t)es.x * 8 + t];

        float xv[4], p[4];
#pragma unroll
        for (int j = 0; j < 4; ++j) {
            const int hc = j * 64 + lane;
            const float v = xlrow[hc];
            xv[j] = v;
            float s = v + xrr[j];
#pragma unroll
            for (int t = 0; t < 8; ++t) s += ea[t] * sWe[t * 256 + hc];
            s = (s > 0.f) ? s : LR_SLOPE * s;
            p[j] = s * sAtt[hc];
        }
        // 64-lane butterfly: p[j] becomes the head-j score on every lane
#pragma unroll
        for (int off = 1; off < 64; off <<= 1) {
#pragma unroll
            for (int j = 0; j < 4; ++j)
                p[j] += __shfl_xor(p[j], off, 64);
        }

        if (H == 1) {
            const float s = p[0] + p[1] + p[2] + p[3];
            if (s <= m[0]) {                 // wave-uniform branch
                const float w = __expf(s - m[0]);
                den[0] += w;
#pragma unroll
                for (int j = 0; j < 4; ++j) acc[j] += w * xv[j];
            } else {
                const float sc = __expf(m[0] - s);  // first edge: exp(-inf)=0
                den[0] = den[0] * sc + 1.f;
#pragma unroll
                for (int j = 0; j < 4; ++j) acc[j] = acc[j] * sc + xv[j];
                m[0] = s;
            }
        } else {
#pragma unroll
            for (int j = 0; j < 4; ++j) {
                const float s = p[j];
                if (s <= m[j]) {
                    const float w = __expf(s - m[j]);
                    den[j] += w;
                    acc[j] += w * xv[j];
                } else {
                    const float sc = __expf(m[j] - s);
                    den[j] = den[j] * sc + 1.f;
                    acc[j] = acc[j] * sc + xv[j];
                    m[j] = s;
                }
            }
        }
    }

#pragma unroll
    for (int j = 0; j < 4; ++j) {
        const int hc = j * 64 + lane;
        const float dn = (H == 1) ? den[0] : den[j];
        float v = (dn > 0.f) ? acc[j] / dn : 0.f;
        v += sBias[hc];
        v = fmaxf(v, 0.f);
        out[(size_t)n * 256 + hc] = v;
    }
}

extern "C" void kernel_launch(void* const* d_in, const int* in_sizes, int n_in,
                              void* d_out, int out_size, void* d_ws, size_t ws_size,
                              hipStream_t stream)
{
    const float* x     = (const float*)d_in[0];
    const int*   eidx  = (const int*)d_in[1];
    const float* eattr = (const float*)d_in[2];
    const float* W1  = (const float*)d_in[3];
    const float* b1  = (const float*)d_in[4];
    const float* W2  = (const float*)d_in[5];
    const float* b2  = (const float*)d_in[6];
    const float* Wl1 = (const float*)d_in[7];
    const float* bl1 = (const float*)d_in[8];
    const float* Wr1 = (const float*)d_in[9];
    const float* br1 = (const float*)d_in[10];
    const float* We1 = (const float*)d_in[11];
    const float* att1 = (const float*)d_in[12];
    const float* bias1 = (const float*)d_in[13];
    const float* Wl2 = (const float*)d_in[14];
    const float* bl2 = (const float*)d_in[15];
    const float* Wr2 = (const float*)d_in[16];
    const float* br2 = (const float*)d_in[17];
    const float* We2 = (const float*)d_in[18];
    const float* att2 = (const float*)d_in[19];
    const float* bias2 = (const float*)d_in[20];

    const int N = in_sizes[0] / 32;        // 50000
    const int E = in_sizes[2] / 8;         // 800000
    const int* src = eidx;
    const int* dst = eidx + E;

    // ---- workspace layout (bytes, 256-aligned) ----
    auto align256 = [](size_t v) { return (v + 255) & ~(size_t)255; };
    char* ws = (char*)d_ws;
    size_t off = 0;
    float* h1 = (float*)(ws + off);    off += align256((size_t)N * 64 * 4);
    float* h2 = (float*)(ws + off);    off += align256((size_t)N * 64 * 4);
    float* xl = (float*)(ws + off);    off += align256((size_t)N * 256 * 4);
    float* xr = (float*)(ws + off);    off += align256((size_t)N * 256 * 4);
    float* out1 = (float*)(ws + off);  off += align256((size_t)N * 256 * 4);
    int* deg = (int*)(ws + off);       off += align256((size_t)N * 4);
    int* rowptr = (int*)(ws + off);    off += align256((size_t)(N + 1) * 4);
    int* cursor = (int*)(ws + off);    off += align256((size_t)N * 4);
    int2* eord = (int2*)(ws + off);    off += align256((size_t)E * 8);
    (void)ws_size;

    float* outf = (float*)d_out;

    auto gemm = [&](const float* A, const float* W, const float* bias,
                    float* out, int M, int Nc, int K, int relu) {
        dim3 grid((M + 63) / 64, Nc / 64);
        gemm_bias_act<<<grid, 256, 0, stream>>>(A, W, bias, out, M, Nc, K, relu);
    };

    const int egrid1 = (E + 255) / 256;
    const int ngrid4 = (N + 3) / 4;

    // ---- CSR build (shared by both GAT layers: same graph) ----
    hipMemsetAsync(deg, 0, (size_t)N * 4, stream);
    hist_k<<<egrid1, 256, 0, stream>>>(dst, deg, E);
    exscan_k<<<1, 1024, 0, stream>>>(deg, rowptr, cursor, N);
    scatter_k<<<egrid1, 256, 0, stream>>>(src, dst, cursor, eord, E);

    // ---- MLP encoder ----
    gemm(x,  W1, b1, h1, N, 64, 32, 1);
    gemm(h1, W2, b2, h2, N, 64, 64, 1);

    // ---- GAT layer 1 (H=4, C=64) ----
    gemm(h2, Wl1, bl1, xl, N, 256, 64, 0);
    gemm(h2, Wr1, br1, xr, N, 256, 64, 0);
    node_gat_k<4><<<ngrid4, 256, 0, stream>>>(xl, xr, eattr, We1, att1, bias1,
                                              rowptr, eord, out1, N);

    // ---- GAT layer 2 (H=1, C=256) ----
    gemm(out1, Wl2, bl2, xl, N, 256, 256, 0);
    gemm(out1, Wr2, br2, xr, N, 256, 256, 0);
    node_gat_k<1><<<ngrid4, 256, 0, stream>>>(xl, xr, eattr, We2, att2, bias2,
                                              rowptr, eord, outf, N);
}

// Round 3
// 733.781 us; speedup vs baseline: 3.6280x; 1.4069x over previous
//
#include <hip/hip_runtime.h>
#include <hip/hip_bf16.h>
#include <math.h>

#define LR_SLOPE 0.2f

// ---------- generic tiled GEMM: out = act(A[M,K] @ W[K,N] + bias[N]) ----------
// 64x64 tile, 256 threads, 4x4 per-thread micro tile, K tiled by 16.
__global__ __launch_bounds__(256) void gemm_bias_act(
    const float* __restrict__ A, const float* __restrict__ W,
    const float* __restrict__ bias, float* __restrict__ out,
    int M, int N, int K, int do_relu)
{
    __shared__ float As[16][64];   // [k][m]
    __shared__ float Ws[16][64];   // [k][n]
    const int tid = threadIdx.x;
    const int tx = tid & 15;       // n-dim
    const int ty = tid >> 4;       // m-dim
    const int row0 = blockIdx.x * 64;
    const int col0 = blockIdx.y * 64;

    float acc[4][4] = {{0.f}};

    for (int kk = 0; kk < K; kk += 16) {
        {
            const int ra = tid >> 2;
            const int ka = (tid & 3) << 2;
            float4 v = make_float4(0.f, 0.f, 0.f, 0.f);
            const int r = row0 + ra;
            if (r < M)
                v = *reinterpret_cast<const float4*>(&A[(size_t)r * K + kk + ka]);
            As[ka + 0][ra] = v.x;
            As[ka + 1][ra] = v.y;
            As[ka + 2][ra] = v.z;
            As[ka + 3][ra] = v.w;
        }
        {
            const int rw = tid >> 4;
            const int cw = (tid & 15) << 2;
            float4 v = *reinterpret_cast<const float4*>(
                &W[(size_t)(kk + rw) * N + col0 + cw]);
            *reinterpret_cast<float4*>(&Ws[rw][cw]) = v;
        }
        __syncthreads();
#pragma unroll
        for (int k = 0; k < 16; ++k) {
            const float4 a = *reinterpret_cast<const float4*>(&As[k][ty * 4]);
            const float4 b = *reinterpret_cast<const float4*>(&Ws[k][tx * 4]);
            const float av[4] = {a.x, a.y, a.z, a.w};
            const float bv[4] = {b.x, b.y, b.z, b.w};
#pragma unroll
            for (int i = 0; i < 4; ++i)
#pragma unroll
                for (int j = 0; j < 4; ++j)
                    acc[i][j] += av[i] * bv[j];
        }
        __syncthreads();
    }

#pragma unroll
    for (int i = 0; i < 4; ++i) {
        const int r = row0 + ty * 4 + i;
        if (r >= M) continue;
#pragma unroll
        for (int j = 0; j < 4; ++j) {
            const int c = col0 + tx * 4 + j;
            float v = acc[i][j] + bias[c];
            if (do_relu) v = fmaxf(v, 0.f);
            out[(size_t)r * N + c] = v;
        }
    }
}

// ---------- CSR build ----------
__global__ void hist_k(const int* __restrict__ dst, int* __restrict__ deg, int E)
{
    const int e = blockIdx.x * blockDim.x + threadIdx.x;
    if (e < E) atomicAdd(&deg[dst[e]], 1);
}

// single-block exclusive scan over N entries -> rowptr[0..N], cursor copy
__global__ __launch_bounds__(1024) void exscan_k(
    const int* __restrict__ deg, int* __restrict__ rowptr,
    int* __restrict__ cursor, int N)
{
    __shared__ int buf[1024];
    __shared__ int carry_s;
    if (threadIdx.x == 0) carry_s = 0;
    __syncthreads();
    for (int base = 0; base < N; base += 1024) {
        const int i = base + (int)threadIdx.x;
        const int v = (i < N) ? deg[i] : 0;
        buf[threadIdx.x] = v;
        __syncthreads();
        for (int off = 1; off < 1024; off <<= 1) {
            int t = (threadIdx.x >= (unsigned)off) ? buf[threadIdx.x - off] : 0;
            __syncthreads();
            buf[threadIdx.x] += t;
            __syncthreads();
        }
        const int incl = buf[threadIdx.x];
        const int excl = incl - v;
        const int carry = carry_s;
        if (i < N) { rowptr[i] = carry + excl; cursor[i] = carry + excl; }
        __syncthreads();
        if (threadIdx.x == 1023) carry_s = carry + incl;
        __syncthreads();
    }
    if (threadIdx.x == 0) rowptr[N] = carry_s;
}

// scatter (edge, src) pairs into dst-sorted order
__global__ void scatter_k(const int* __restrict__ src, const int* __restrict__ dst,
                          int* __restrict__ cursor, int2* __restrict__ eord, int E)
{
    const int e = blockIdx.x * blockDim.x + threadIdx.x;
    if (e >= E) return;
    const int d = dst[e];
    const int p = atomicAdd(&cursor[d], 1);
    eord[p] = make_int2(e, src[e]);
}

// ---------- fused node-centric GATv2: score + online softmax + aggregate ----------
// One wave per dst node. HC = 256 channels total.
// Lane -> channel map: 4 CONTIGUOUS channels per lane, single head per lane.
//   H=4 (C=64):  head = lane>>4, hc0 = head*64 + (lane&15)*4  -> 4-step reduce
//   H=1 (C=256): hc0 = lane*4                                  -> 6-step reduce
template <int H>
__global__ __launch_bounds__(256, 4) void node_gat_k(
    const float* __restrict__ xl, const float* __restrict__ xr,
    const float* __restrict__ eattr, const float* __restrict__ We,
    const float* __restrict__ att, const float* __restrict__ bias,
    const int* __restrict__ rowptr, const int2* __restrict__ eord,
    float* __restrict__ out, int N)
{
    const int lane = threadIdx.x & 63;
    const int n = blockIdx.x * 4 + (threadIdx.x >> 6);
    if (n >= N) return;

    const int hc0 = (H == 4) ? (((lane >> 4) << 6) + ((lane & 15) << 2))
                             : (lane << 2);

    // hoist We[:, hc0..hc0+3], att, xr row into registers (no LDS at all)
    float we[8][4];
#pragma unroll
    for (int t = 0; t < 8; ++t) {
        const float4 v = *reinterpret_cast<const float4*>(&We[t * 256 + hc0]);
        we[t][0] = v.x; we[t][1] = v.y; we[t][2] = v.z; we[t][3] = v.w;
    }
    const float4 a4 = *reinterpret_cast<const float4*>(&att[hc0]);
    const float av[4] = {a4.x, a4.y, a4.z, a4.w};
    const float4 r4 = *reinterpret_cast<const float4*>(&xr[(size_t)n * 256 + hc0]);
    const float xrv[4] = {r4.x, r4.y, r4.z, r4.w};

    float acc[4] = {0.f, 0.f, 0.f, 0.f};
    float m = -INFINITY, den = 0.f;

    // per-edge score: leaky(xl+xr+eattr@We) . att, reduced over this lane's head
    auto score = [&](const int2 es, float (&xv)[4]) -> float {
        const float4 x4 = *reinterpret_cast<const float4*>(
            &xl[(size_t)es.y * 256 + hc0]);
        xv[0] = x4.x; xv[1] = x4.y; xv[2] = x4.z; xv[3] = x4.w;
        const float4 e0 = *reinterpret_cast<const float4*>(&eattr[(size_t)es.x * 8]);
        const float4 e1 = *reinterpret_cast<const float4*>(&eattr[(size_t)es.x * 8 + 4]);
        const float ea[8] = {e0.x, e0.y, e0.z, e0.w, e1.x, e1.y, e1.z, e1.w};
        float p = 0.f;
#pragma unroll
        for (int c = 0; c < 4; ++c) {
            float s = xv[c] + xrv[c];
#pragma unroll
            for (int t = 0; t < 8; ++t) s = fmaf(ea[t], we[t][c], s);
            s = fmaxf(s, LR_SLOPE * s);          // leaky relu (slope < 1)
            p = fmaf(s, av[c], p);
        }
#pragma unroll
        for (int off = 1; off < (H == 4 ? 16 : 64); off <<= 1)
            p += __shfl_xor(p, off, 64);
        return p;
    };

    const int k0 = rowptr[n], k1 = rowptr[n + 1];
    int k = k0;
    for (; k + 2 <= k1; k += 2) {               // 2-edge unroll for ILP
        const int2 es0 = eord[k];
        const int2 es1 = eord[k + 1];
        float xv0[4], xv1[4];
        const float s0 = score(es0, xv0);
        const float s1 = score(es1, xv1);
        const float nm = fmaxf(m, fmaxf(s0, s1));
        const float sc = __expf(m - nm);         // branchless online softmax
        const float w0 = __expf(s0 - nm);
        const float w1 = __expf(s1 - nm);
        den = fmaf(den, sc, w0 + w1);
#pragma unroll
        for (int c = 0; c < 4; ++c)
            acc[c] = fmaf(acc[c], sc, fmaf(w0, xv0[c], w1 * xv1[c]));
        m = nm;
    }
    if (k < k1) {                                // odd-degree tail
        const int2 es0 = eord[k];
        float xv0[4];
        const float s0 = score(es0, xv0);
        const float nm = fmaxf(m, s0);
        const float sc = __expf(m - nm);
        const float w0 = __expf(s0 - nm);
        den = fmaf(den, sc, w0);
#pragma unroll
        for (int c = 0; c < 4; ++c)
            acc[c] = fmaf(acc[c], sc, w0 * xv0[c]);
        m = nm;
    }

    const float inv = (den > 0.f) ? 1.f / den : 0.f;   // deg-0: out = relu(bias)
    const float4 b4 = *reinterpret_cast<const float4*>(&bias[hc0]);
    float4 o;
    o.x = fmaxf(fmaf(acc[0], inv, b4.x), 0.f);
    o.y = fmaxf(fmaf(acc[1], inv, b4.y), 0.f);
    o.z = fmaxf(fmaf(acc[2], inv, b4.z), 0.f);
    o.w = fmaxf(fmaf(acc[3], inv, b4.w), 0.f);
    *reinterpret_cast<float4*>(&out[(size_t)n * 256 + hc0]) = o;
}

extern "C" void kernel_launch(void* const* d_in, const int* in_sizes, int n_in,
                              void* d_out, int out_size, void* d_ws, size_t ws_size,
                              hipStream_t stream)
{
    const float* x     = (const float*)d_in[0];
    const int*   eidx  = (const int*)d_in[1];
    const float* eattr = (const float*)d_in[2];
    const float* W1  = (const float*)d_in[3];
    const float* b1  = (const float*)d_in[4];
    const float* W2  = (const float*)d_in[5];
    const float* b2  = (const float*)d_in[6];
    const float* Wl1 = (const float*)d_in[7];
    const float* bl1 = (const float*)d_in[8];
    const float* Wr1 = (const float*)d_in[9];
    const float* br1 = (const float*)d_in[10];
    const float* We1 = (const float*)d_in[11];
    const float* att1 = (const float*)d_in[12];
    const float* bias1 = (const float*)d_in[13];
    const float* Wl2 = (const float*)d_in[14];
    const float* bl2 = (const float*)d_in[15];
    const float* Wr2 = (const float*)d_in[16];
    const float* br2 = (const float*)d_in[17];
    const float* We2 = (const float*)d_in[18];
    const float* att2 = (const float*)d_in[19];
    const float* bias2 = (const float*)d_in[20];

    const int N = in_sizes[0] / 32;        // 50000
    const int E = in_sizes[2] / 8;         // 800000
    const int* src = eidx;
    const int* dst = eidx + E;

    // ---- workspace layout (bytes, 256-aligned) ----
    auto align256 = [](size_t v) { return (v + 255) & ~(size_t)255; };
    char* ws = (char*)d_ws;
    size_t off = 0;
    float* h1 = (float*)(ws + off);    off += align256((size_t)N * 64 * 4);
    float* h2 = (float*)(ws + off);    off += align256((size_t)N * 64 * 4);
    float* xl = (float*)(ws + off);    off += align256((size_t)N * 256 * 4);
    float* xr = (float*)(ws + off);    off += align256((size_t)N * 256 * 4);
    float* out1 = (float*)(ws + off);  off += align256((size_t)N * 256 * 4);
    int* deg = (int*)(ws + off);       off += align256((size_t)N * 4);
    int* rowptr = (int*)(ws + off);    off += align256((size_t)(N + 1) * 4);
    int* cursor = (int*)(ws + off);    off += align256((size_t)N * 4);
    int2* eord = (int2*)(ws + off);    off += align256((size_t)E * 8);
    (void)ws_size;

    float* outf = (float*)d_out;

    auto gemm = [&](const float* A, const float* W, const float* bias,
                    float* out, int M, int Nc, int K, int relu) {
        dim3 grid((M + 63) / 64, Nc / 64);
        gemm_bias_act<<<grid, 256, 0, stream>>>(A, W, bias, out, M, Nc, K, relu);
    };

    const int egrid1 = (E + 255) / 256;
    const int ngrid4 = (N + 3) / 4;

    // ---- CSR build (shared by both GAT layers: same graph) ----
    hipMemsetAsync(deg, 0, (size_t)N * 4, stream);
    hist_k<<<egrid1, 256, 0, stream>>>(dst, deg, E);
    exscan_k<<<1, 1024, 0, stream>>>(deg, rowptr, cursor, N);
    scatter_k<<<egrid1, 256, 0, stream>>>(src, dst, cursor, eord, E);

    // ---- MLP encoder ----
    gemm(x,  W1, b1, h1, N, 64, 32, 1);
    gemm(h1, W2, b2, h2, N, 64, 64, 1);

    // ---- GAT layer 1 (H=4, C=64) ----
    gemm(h2, Wl1, bl1, xl, N, 256, 64, 0);
    gemm(h2, Wr1, br1, xr, N, 256, 64, 0);
    node_gat_k<4><<<ngrid4, 256, 0, stream>>>(xl, xr, eattr, We1, att1, bias1,
                                              rowptr, eord, out1, N);

    // ---- GAT layer 2 (H=1, C=256) ----
    gemm(out1, Wl2, bl2, xl, N, 256, 256, 0);
    gemm(out1, Wr2, br2, xr, N, 256, 256, 0);
    node_gat_k<1><<<ngrid4, 256, 0, stream>>>(xl, xr, eattr, We2, att2, bias2,
                                              rowptr, eord, outf, N);
}

// Round 4
// 607.691 us; speedup vs baseline: 4.3807x; 1.2075x over previous
//
#include <hip/hip_runtime.h>
#include <hip/hip_bf16.h>
#include <math.h>

#define LR_SLOPE 0.2f

// ---------- small GEMM (MLP, N=64): out = act(A@W + bias) ----------
// 64x64 tile, 256 threads, 4x4 micro, K tiled by 16.
__global__ __launch_bounds__(256) void gemm_bias_act(
    const float* __restrict__ A, const float* __restrict__ W,
    const float* __restrict__ bias, float* __restrict__ out,
    int M, int N, int K, int do_relu)
{
    __shared__ float As[16][64];
    __shared__ float Ws[16][64];
    const int tid = threadIdx.x;
    const int tx = tid & 15;
    const int ty = tid >> 4;
    const int row0 = blockIdx.x * 64;
    const int col0 = blockIdx.y * 64;

    float acc[4][4] = {{0.f}};

    for (int kk = 0; kk < K; kk += 16) {
        {
            const int ra = tid >> 2;
            const int ka = (tid & 3) << 2;
            float4 v = make_float4(0.f, 0.f, 0.f, 0.f);
            const int r = row0 + ra;
            if (r < M)
                v = *reinterpret_cast<const float4*>(&A[(size_t)r * K + kk + ka]);
            As[ka + 0][ra] = v.x;
            As[ka + 1][ra] = v.y;
            As[ka + 2][ra] = v.z;
            As[ka + 3][ra] = v.w;
        }
        {
            const int rw = tid >> 4;
            const int cw = (tid & 15) << 2;
            float4 v = *reinterpret_cast<const float4*>(
                &W[(size_t)(kk + rw) * N + col0 + cw]);
            *reinterpret_cast<float4*>(&Ws[rw][cw]) = v;
        }
        __syncthreads();
#pragma unroll
        for (int k = 0; k < 16; ++k) {
            const float4 a = *reinterpret_cast<const float4*>(&As[k][ty * 4]);
            const float4 b = *reinterpret_cast<const float4*>(&Ws[k][tx * 4]);
            const float av[4] = {a.x, a.y, a.z, a.w};
            const float bv[4] = {b.x, b.y, b.z, b.w};
#pragma unroll
            for (int i = 0; i < 4; ++i)
#pragma unroll
                for (int j = 0; j < 4; ++j)
                    acc[i][j] += av[i] * bv[j];
        }
        __syncthreads();
    }

#pragma unroll
    for (int i = 0; i < 4; ++i) {
        const int r = row0 + ty * 4 + i;
        if (r >= M) continue;
#pragma unroll
        for (int j = 0; j < 4; ++j) {
            const int c = col0 + tx * 4 + j;
            float v = acc[i][j] + bias[c];
            if (do_relu) v = fmaxf(v, 0.f);
            out[(size_t)r * N + c] = v;
        }
    }
}

// ---------- big dual GEMM: {out0,out1} = A @ {W0,W1} + {b0,b1} ----------
// 128x128 tile, 256 threads, 8x8 micro, BK=16. blockIdx.z picks W/bias/out.
__global__ __launch_bounds__(256, 2) void gemm128_dual(
    const float* __restrict__ A,
    const float* __restrict__ W0, const float* __restrict__ b0,
    float* __restrict__ out0,
    const float* __restrict__ W1, const float* __restrict__ b1,
    float* __restrict__ out1,
    int M, int N, int K)
{
    const float* __restrict__ W    = blockIdx.z ? W1 : W0;
    const float* __restrict__ bias = blockIdx.z ? b1 : b0;
    float* __restrict__ out        = blockIdx.z ? out1 : out0;

    __shared__ float As[16][128];
    __shared__ float Ws[16][132];   // +4 pad to vary bank position with k

    const int tid = threadIdx.x;
    const int tx = tid & 15;        // col group (8 cols)
    const int ty = tid >> 4;        // row group (8 rows)
    const int row0 = blockIdx.x * 128;
    const int col0 = blockIdx.y * 128;

    float acc[8][8] = {{0.f}};

    const int ra = tid >> 1;            // A row this thread loads
    const int ka = (tid & 1) << 3;      // k offset 0 or 8
    const int rw = tid >> 4;            // W row this thread loads
    const int cw = (tid & 15) << 3;     // W col offset

    for (int kk = 0; kk < K; kk += 16) {
        {
            const int r = row0 + ra;
            float4 a0 = make_float4(0.f, 0.f, 0.f, 0.f), a1 = a0;
            if (r < M) {
                a0 = *reinterpret_cast<const float4*>(&A[(size_t)r * K + kk + ka]);
                a1 = *reinterpret_cast<const float4*>(&A[(size_t)r * K + kk + ka + 4]);
            }
            As[ka + 0][ra] = a0.x; As[ka + 1][ra] = a0.y;
            As[ka + 2][ra] = a0.z; As[ka + 3][ra] = a0.w;
            As[ka + 4][ra] = a1.x; As[ka + 5][ra] = a1.y;
            As[ka + 6][ra] = a1.z; As[ka + 7][ra] = a1.w;
        }
        {
            const float4 w0 = *reinterpret_cast<const float4*>(
                &W[(size_t)(kk + rw) * N + col0 + cw]);
            const float4 w1 = *reinterpret_cast<const float4*>(
                &W[(size_t)(kk + rw) * N + col0 + cw + 4]);
            *reinterpret_cast<float4*>(&Ws[rw][cw]) = w0;
            *reinterpret_cast<float4*>(&Ws[rw][cw + 4]) = w1;
        }
        __syncthreads();
#pragma unroll
        for (int k = 0; k < 16; ++k) {
            float a[8], b[8];
            *reinterpret_cast<float4*>(&a[0]) =
                *reinterpret_cast<const float4*>(&As[k][ty * 8]);
            *reinterpret_cast<float4*>(&a[4]) =
                *reinterpret_cast<const float4*>(&As[k][ty * 8 + 4]);
            *reinterpret_cast<float4*>(&b[0]) =
                *reinterpret_cast<const float4*>(&Ws[k][tx * 8]);
            *reinterpret_cast<float4*>(&b[4]) =
                *reinterpret_cast<const float4*>(&Ws[k][tx * 8 + 4]);
#pragma unroll
            for (int i = 0; i < 8; ++i)
#pragma unroll
                for (int j = 0; j < 8; ++j)
                    acc[i][j] = fmaf(a[i], b[j], acc[i][j]);
        }
        __syncthreads();
    }

    const int cbase = col0 + tx * 8;
    float bv[8];
    *reinterpret_cast<float4*>(&bv[0]) =
        *reinterpret_cast<const float4*>(&bias[cbase]);
    *reinterpret_cast<float4*>(&bv[4]) =
        *reinterpret_cast<const float4*>(&bias[cbase + 4]);
#pragma unroll
    for (int i = 0; i < 8; ++i) {
        const int r = row0 + ty * 8 + i;
        if (r >= M) continue;
        float4 o0, o1;
        o0.x = acc[i][0] + bv[0]; o0.y = acc[i][1] + bv[1];
        o0.z = acc[i][2] + bv[2]; o0.w = acc[i][3] + bv[3];
        o1.x = acc[i][4] + bv[4]; o1.y = acc[i][5] + bv[5];
        o1.z = acc[i][6] + bv[6]; o1.w = acc[i][7] + bv[7];
        *reinterpret_cast<float4*>(&out[(size_t)r * N + cbase]) = o0;
        *reinterpret_cast<float4*>(&out[(size_t)r * N + cbase + 4]) = o1;
    }
}

// ---------- CSR build ----------
__global__ void hist_k(const int* __restrict__ dst, int* __restrict__ deg, int E)
{
    const int e = blockIdx.x * blockDim.x + threadIdx.x;
    if (e < E) atomicAdd(&deg[dst[e]], 1);
}

// 3-phase scan: per-block scan -> top scan -> add-back
__global__ void scan1_k(const int* __restrict__ deg, int* __restrict__ rowptr,
                        int* __restrict__ bsum, int N)
{
    __shared__ int buf[256];
    const int i = blockIdx.x * 256 + threadIdx.x;
    const int v = (i < N) ? deg[i] : 0;
    buf[threadIdx.x] = v;
    __syncthreads();
#pragma unroll
    for (int off = 1; off < 256; off <<= 1) {
        const int t = (threadIdx.x >= (unsigned)off) ? buf[threadIdx.x - off] : 0;
        __syncthreads();
        buf[threadIdx.x] += t;
        __syncthreads();
    }
    if (i < N) rowptr[i] = buf[threadIdx.x] - v;   // exclusive, block-local
    if (threadIdx.x == 255) bsum[blockIdx.x] = buf[255];
}

__global__ void scan2_k(int* __restrict__ bsum, int nb)
{
    __shared__ int buf[256];
    const int v = (threadIdx.x < (unsigned)nb) ? bsum[threadIdx.x] : 0;
    buf[threadIdx.x] = v;
    __syncthreads();
#pragma unroll
    for (int off = 1; off < 256; off <<= 1) {
        const int t = (threadIdx.x >= (unsigned)off) ? buf[threadIdx.x - off] : 0;
        __syncthreads();
        buf[threadIdx.x] += t;
        __syncthreads();
    }
    if (threadIdx.x < (unsigned)nb) bsum[threadIdx.x] = buf[threadIdx.x] - v;
}

__global__ void scan3_k(int* __restrict__ rowptr, const int* __restrict__ bsum,
                        int* __restrict__ cursor, int N, int E)
{
    const int i = blockIdx.x * 256 + threadIdx.x;
    if (i < N) {
        const int r = rowptr[i] + bsum[blockIdx.x];
        rowptr[i] = r;
        cursor[i] = r;
    }
    if (i == 0) rowptr[N] = E;
}

// scatter (edge, src) pairs into dst-sorted order
__global__ void scatter_k(const int* __restrict__ src, const int* __restrict__ dst,
                          int* __restrict__ cursor, int2* __restrict__ eord, int E)
{
    const int e = blockIdx.x * blockDim.x + threadIdx.x;
    if (e >= E) return;
    const int d = dst[e];
    const int p = atomicAdd(&cursor[d], 1);
    eord[p] = make_int2(e, src[e]);
}

// ---------- fused node-centric GATv2 ----------
// One wave per dst node; lane owns 4 contiguous channels of one head.
//   H=4: head = lane>>4, hc0 = head*64 + (lane&15)*4  (4-step reduce)
//   H=1: hc0 = lane*4                                  (6-step reduce)
template <int H>
__global__ __launch_bounds__(256, 4) void node_gat_k(
    const float* __restrict__ xl, const float* __restrict__ xr,
    const float* __restrict__ eattr, const float* __restrict__ We,
    const float* __restrict__ att, const float* __restrict__ bias,
    const int* __restrict__ rowptr, const int2* __restrict__ eord,
    float* __restrict__ out, int N)
{
    const int lane = threadIdx.x & 63;
    const int n = blockIdx.x * 4 + (threadIdx.x >> 6);
    if (n >= N) return;

    const int hc0 = (H == 4) ? (((lane >> 4) << 6) + ((lane & 15) << 2))
                             : (lane << 2);

    float we[8][4];
#pragma unroll
    for (int t = 0; t < 8; ++t) {
        const float4 v = *reinterpret_cast<const float4*>(&We[t * 256 + hc0]);
        we[t][0] = v.x; we[t][1] = v.y; we[t][2] = v.z; we[t][3] = v.w;
    }
    const float4 a4 = *reinterpret_cast<const float4*>(&att[hc0]);
    const float av[4] = {a4.x, a4.y, a4.z, a4.w};
    const float4 r4 = *reinterpret_cast<const float4*>(&xr[(size_t)n * 256 + hc0]);
    const float xrv[4] = {r4.x, r4.y, r4.z, r4.w};

    float acc[4] = {0.f, 0.f, 0.f, 0.f};
    float m = -INFINITY, den = 0.f;

    // stage loads for one edge
    auto load_e = [&](const int2 es, float (&xv)[4], float (&ea)[8]) {
        const float4 x4 = *reinterpret_cast<const float4*>(
            &xl[(size_t)es.y * 256 + hc0]);
        xv[0] = x4.x; xv[1] = x4.y; xv[2] = x4.z; xv[3] = x4.w;
        const float4 e0 = *reinterpret_cast<const float4*>(&eattr[(size_t)es.x * 8]);
        const float4 e1 = *reinterpret_cast<const float4*>(&eattr[(size_t)es.x * 8 + 4]);
        ea[0] = e0.x; ea[1] = e0.y; ea[2] = e0.z; ea[3] = e0.w;
        ea[4] = e1.x; ea[5] = e1.y; ea[6] = e1.z; ea[7] = e1.w;
    };
    // score from staged data (head-local butterfly reduce)
    auto sc_of = [&](const float (&xv)[4], const float (&ea)[8]) -> float {
        float p = 0.f;
#pragma unroll
        for (int c = 0; c < 4; ++c) {
            float s = xv[c] + xrv[c];
#pragma unroll
            for (int t = 0; t < 8; ++t) s = fmaf(ea[t], we[t][c], s);
            s = fmaxf(s, LR_SLOPE * s);
            p = fmaf(s, av[c], p);
        }
#pragma unroll
        for (int off = 1; off < (H == 4 ? 16 : 64); off <<= 1)
            p += __shfl_xor(p, off, 64);
        return p;
    };

    const int k0 = rowptr[n], k1 = rowptr[n + 1];
    int k = k0;
    for (; k + 4 <= k1; k += 4) {
        const int2 es0 = eord[k],     es1 = eord[k + 1];
        const int2 es2 = eord[k + 2], es3 = eord[k + 3];
        float x0[4], x1[4], x2[4], x3[4];
        float ea0[8], ea1[8], ea2[8], ea3[8];
        load_e(es0, x0, ea0); load_e(es1, x1, ea1);
        load_e(es2, x2, ea2); load_e(es3, x3, ea3);
        const float s0 = sc_of(x0, ea0);
        const float s1 = sc_of(x1, ea1);
        const float s2 = sc_of(x2, ea2);
        const float s3 = sc_of(x3, ea3);
        const float nm = fmaxf(fmaxf(m, fmaxf(s0, s1)), fmaxf(s2, s3));
        const float sc = __expf(m - nm);
        const float w0 = __expf(s0 - nm), w1 = __expf(s1 - nm);
        const float w2 = __expf(s2 - nm), w3 = __expf(s3 - nm);
        den = fmaf(den, sc, (w0 + w1) + (w2 + w3));
#pragma unroll
        for (int c = 0; c < 4; ++c)
            acc[c] = fmaf(acc[c], sc,
                     fmaf(w0, x0[c], fmaf(w1, x1[c], fmaf(w2, x2[c], w3 * x3[c]))));
        m = nm;
    }
    for (; k < k1; ++k) {
        const int2 es0 = eord[k];
        float x0[4]; float ea0[8];
        load_e(es0, x0, ea0);
        const float s0 = sc_of(x0, ea0);
        const float nm = fmaxf(m, s0);
        const float sc = __expf(m - nm);
        const float w0 = __expf(s0 - nm);
        den = fmaf(den, sc, w0);
#pragma unroll
        for (int c = 0; c < 4; ++c)
            acc[c] = fmaf(acc[c], sc, w0 * x0[c]);
        m = nm;
    }

    const float inv = (den > 0.f) ? 1.f / den : 0.f;
    const float4 b4 = *reinterpret_cast<const float4*>(&bias[hc0]);
    float4 o;
    o.x = fmaxf(fmaf(acc[0], inv, b4.x), 0.f);
    o.y = fmaxf(fmaf(acc[1], inv, b4.y), 0.f);
    o.z = fmaxf(fmaf(acc[2], inv, b4.z), 0.f);
    o.w = fmaxf(fmaf(acc[3], inv, b4.w), 0.f);
    *reinterpret_cast<float4*>(&out[(size_t)n * 256 + hc0]) = o;
}

extern "C" void kernel_launch(void* const* d_in, const int* in_sizes, int n_in,
                              void* d_out, int out_size, void* d_ws, size_t ws_size,
                              hipStream_t stream)
{
    const float* x     = (const float*)d_in[0];
    const int*   eidx  = (const int*)d_in[1];
    const float* eattr = (const float*)d_in[2];
    const float* W1  = (const float*)d_in[3];
    const float* b1  = (const float*)d_in[4];
    const float* W2  = (const float*)d_in[5];
    const float* b2  = (const float*)d_in[6];
    const float* Wl1 = (const float*)d_in[7];
    const float* bl1 = (const float*)d_in[8];
    const float* Wr1 = (const float*)d_in[9];
    const float* br1 = (const float*)d_in[10];
    const float* We1 = (const float*)d_in[11];
    const float* att1 = (const float*)d_in[12];
    const float* bias1 = (const float*)d_in[13];
    const float* Wl2 = (const float*)d_in[14];
    const float* bl2 = (const float*)d_in[15];
    const float* Wr2 = (const float*)d_in[16];
    const float* br2 = (const float*)d_in[17];
    const float* We2 = (const float*)d_in[18];
    const float* att2 = (const float*)d_in[19];
    const float* bias2 = (const float*)d_in[20];

    const int N = in_sizes[0] / 32;        // 50000
    const int E = in_sizes[2] / 8;         // 800000
    const int* src = eidx;
    const int* dst = eidx + E;

    // ---- workspace layout ----
    auto align256 = [](size_t v) { return (v + 255) & ~(size_t)255; };
    char* ws = (char*)d_ws;
    size_t off = 0;
    float* h1 = (float*)(ws + off);    off += align256((size_t)N * 64 * 4);
    float* h2 = (float*)(ws + off);    off += align256((size_t)N * 64 * 4);
    float* xl = (float*)(ws + off);    off += align256((size_t)N * 256 * 4);
    float* xr = (float*)(ws + off);    off += align256((size_t)N * 256 * 4);
    float* out1 = (float*)(ws + off);  off += align256((size_t)N * 256 * 4);
    int* deg = (int*)(ws + off);       off += align256((size_t)N * 4);
    int* rowptr = (int*)(ws + off);    off += align256((size_t)(N + 1) * 4);
    int* cursor = (int*)(ws + off);    off += align256((size_t)N * 4);
    int* bsum = (int*)(ws + off);      off += align256((size_t)1024 * 4);
    int2* eord = (int2*)(ws + off);    off += align256((size_t)E * 8);
    (void)ws_size;

    float* outf = (float*)d_out;

    const int egrid1 = (E + 255) / 256;
    const int ngrid4 = (N + 3) / 4;
    const int nblk = (N + 255) / 256;      // 196

    // ---- CSR build (shared by both GAT layers) ----
    hipMemsetAsync(deg, 0, (size_t)N * 4, stream);
    hist_k<<<egrid1, 256, 0, stream>>>(dst, deg, E);
    scan1_k<<<nblk, 256, 0, stream>>>(deg, rowptr, bsum, N);
    scan2_k<<<1, 256, 0, stream>>>(bsum, nblk);
    scan3_k<<<nblk, 256, 0, stream>>>(rowptr, bsum, cursor, N, E);
    scatter_k<<<egrid1, 256, 0, stream>>>(src, dst, cursor, eord, E);

    // ---- MLP encoder ----
    {
        dim3 g1((N + 63) / 64, 1);
        gemm_bias_act<<<g1, 256, 0, stream>>>(x,  W1, b1, h1, N, 64, 32, 1);
        gemm_bias_act<<<g1, 256, 0, stream>>>(h1, W2, b2, h2, N, 64, 64, 1);
    }

    // ---- GAT layer 1 (H=4, C=64) ----
    {
        dim3 g((N + 127) / 128, 2, 2);
        gemm128_dual<<<g, 256, 0, stream>>>(h2, Wl1, bl1, xl, Wr1, br1, xr,
                                            N, 256, 64);
    }
    node_gat_k<4><<<ngrid4, 256, 0, stream>>>(xl, xr, eattr, We1, att1, bias1,
                                              rowptr, eord, out1, N);

    // ---- GAT layer 2 (H=1, C=256) ----
    {
        dim3 g((N + 127) / 128, 2, 2);
        gemm128_dual<<<g, 256, 0, stream>>>(out1, Wl2, bl2, xl, Wr2, br2, xr,
                                            N, 256, 256);
    }
    node_gat_k<1><<<ngrid4, 256, 0, stream>>>(xl, xr, eattr, We2, att2, bias2,
                                              rowptr, eord, outf, N);
}

// Round 5
// 540.865 us; speedup vs baseline: 4.9220x; 1.1236x over previous
//
#include <hip/hip_runtime.h>
#include <hip/hip_bf16.h>
#include <math.h>

#define LR_SLOPE 0.2f

typedef __attribute__((ext_vector_type(8))) short bf16x8;
typedef __attribute__((ext_vector_type(4))) float f32x4;

// fp32 -> bf16 round-to-nearest-even (bit trick)
__device__ __forceinline__ unsigned short f2bf(float f) {
    unsigned u = __float_as_uint(f);
    u = (u + 0x7FFFu + ((u >> 16) & 1u)) >> 16;
    return (unsigned short)u;
}

// ---------- small GEMM (MLP, N=64): out = act(A@W + bias) ----------
__global__ __launch_bounds__(256) void gemm_bias_act(
    const float* __restrict__ A, const float* __restrict__ W,
    const float* __restrict__ bias, float* __restrict__ out,
    int M, int N, int K, int do_relu)
{
    __shared__ float As[16][64];
    __shared__ float Ws[16][64];
    const int tid = threadIdx.x;
    const int tx = tid & 15;
    const int ty = tid >> 4;
    const int row0 = blockIdx.x * 64;
    const int col0 = blockIdx.y * 64;

    float acc[4][4] = {{0.f}};

    for (int kk = 0; kk < K; kk += 16) {
        {
            const int ra = tid >> 2;
            const int ka = (tid & 3) << 2;
            float4 v = make_float4(0.f, 0.f, 0.f, 0.f);
            const int r = row0 + ra;
            if (r < M)
                v = *reinterpret_cast<const float4*>(&A[(size_t)r * K + kk + ka]);
            As[ka + 0][ra] = v.x;
            As[ka + 1][ra] = v.y;
            As[ka + 2][ra] = v.z;
            As[ka + 3][ra] = v.w;
        }
        {
            const int rw = tid >> 4;
            const int cw = (tid & 15) << 2;
            float4 v = *reinterpret_cast<const float4*>(
                &W[(size_t)(kk + rw) * N + col0 + cw]);
            *reinterpret_cast<float4*>(&Ws[rw][cw]) = v;
        }
        __syncthreads();
#pragma unroll
        for (int k = 0; k < 16; ++k) {
            const float4 a = *reinterpret_cast<const float4*>(&As[k][ty * 4]);
            const float4 b = *reinterpret_cast<const float4*>(&Ws[k][tx * 4]);
            const float av[4] = {a.x, a.y, a.z, a.w};
            const float bv[4] = {b.x, b.y, b.z, b.w};
#pragma unroll
            for (int i = 0; i < 4; ++i)
#pragma unroll
                for (int j = 0; j < 4; ++j)
                    acc[i][j] += av[i] * bv[j];
        }
        __syncthreads();
    }

#pragma unroll
    for (int i = 0; i < 4; ++i) {
        const int r = row0 + ty * 4 + i;
        if (r >= M) continue;
#pragma unroll
        for (int j = 0; j < 4; ++j) {
            const int c = col0 + tx * 4 + j;
            float v = acc[i][j] + bias[c];
            if (do_relu) v = fmaxf(v, 0.f);
            out[(size_t)r * N + c] = v;
        }
    }
}

// ---------- weight transpose + bf16 convert: Wt[n][k] = bf16(W[k][n]) ----------
__global__ void wtrans_k(const float* __restrict__ W, short* __restrict__ Wt,
                         int K, int N)
{
    const int i = blockIdx.x * 256 + threadIdx.x;
    if (i >= N * K) return;
    const int n = i / K, k = i % K;
    Wt[i] = (short)f2bf(W[(size_t)k * N + n]);
}

// ---------- MFMA dual GEMM: {out0,out1} = A @ {W0,W1} + {b0,b1} ----------
// A: fp32 [M][K] (converted to bf16 in staging). Wt*: bf16 [N][K] (pre-transposed).
// 128x128 tile, 4 waves (2x2), each wave 64x64 = 4x4 frags of 16x16.
// LDS layout [kg][row][8]: fragment read = one contiguous ds_read_b128.
//   A-frag: lane = 16*kg + row, holds A[row][kg*8+j]   (m89-verified layout)
//   B-frag: lane = 16*kg + col, holds B[kg*8+j][col] = Wt[col][kg*8+j]
//   C/D:    col = lane&15, row = (lane>>4)*4 + reg
__global__ __launch_bounds__(256) void gemm_mfma_dual(
    const float* __restrict__ A,
    const short* __restrict__ Wt0, const float* __restrict__ b0,
    float* __restrict__ out0,
    const short* __restrict__ Wt1, const float* __restrict__ b1,
    float* __restrict__ out1,
    int M, int N, int K)
{
    const short* __restrict__ Wt   = blockIdx.z ? Wt1 : Wt0;
    const float* __restrict__ bias = blockIdx.z ? b1 : b0;
    float* __restrict__ out        = blockIdx.z ? out1 : out0;

    __shared__ __align__(16) short As[4][128][8];   // 8 KB
    __shared__ __align__(16) short Bs[4][128][8];   // 8 KB

    const int tid = threadIdx.x;
    const int lane = tid & 63;
    const int wid = tid >> 6;
    const int wm = wid >> 1, wn = wid & 1;
    const int row0 = blockIdx.x * 128;
    const int col0 = blockIdx.y * 128;

    f32x4 acc[4][4] = {};

    const int srow = tid & 127;     // row (A) / col (B) this thread stages
    const int skg2 = tid >> 7;      // which 16-k half of the 32-k step

    for (int kk = 0; kk < K; kk += 32) {
        // ---- stage A tile (fp32 -> bf16, 16 k-elems per thread) ----
        {
            const int r = row0 + srow;
            float v[16];
            if (r < M) {
                const float4* p = reinterpret_cast<const float4*>(
                    &A[(size_t)r * K + kk + skg2 * 16]);
                *reinterpret_cast<float4*>(&v[0])  = p[0];
                *reinterpret_cast<float4*>(&v[4])  = p[1];
                *reinterpret_cast<float4*>(&v[8])  = p[2];
                *reinterpret_cast<float4*>(&v[12]) = p[3];
            } else {
#pragma unroll
                for (int j = 0; j < 16; ++j) v[j] = 0.f;
            }
            short s[16];
#pragma unroll
            for (int j = 0; j < 16; ++j) s[j] = (short)f2bf(v[j]);
            *reinterpret_cast<bf16x8*>(&As[skg2 * 2 + 0][srow][0]) =
                *reinterpret_cast<bf16x8*>(&s[0]);
            *reinterpret_cast<bf16x8*>(&As[skg2 * 2 + 1][srow][0]) =
                *reinterpret_cast<bf16x8*>(&s[8]);
        }
        // ---- stage B tile (already bf16: 32B copy) ----
        {
            const float4* p = reinterpret_cast<const float4*>(
                &Wt[(size_t)(col0 + srow) * K + kk + skg2 * 16]);
            *reinterpret_cast<float4*>(&Bs[skg2 * 2 + 0][srow][0]) = p[0];
            *reinterpret_cast<float4*>(&Bs[skg2 * 2 + 1][srow][0]) = p[1];
        }
        __syncthreads();

        const int kg = lane >> 4, li = lane & 15;
        bf16x8 af[4], bfr[4];
#pragma unroll
        for (int mi = 0; mi < 4; ++mi)
            af[mi] = *reinterpret_cast<bf16x8*>(&As[kg][wm * 64 + mi * 16 + li][0]);
#pragma unroll
        for (int ni = 0; ni < 4; ++ni)
            bfr[ni] = *reinterpret_cast<bf16x8*>(&Bs[kg][wn * 64 + ni * 16 + li][0]);
#pragma unroll
        for (int mi = 0; mi < 4; ++mi)
#pragma unroll
            for (int ni = 0; ni < 4; ++ni)
                acc[mi][ni] = __builtin_amdgcn_mfma_f32_16x16x32_bf16(
                    af[mi], bfr[ni], acc[mi][ni], 0, 0, 0);
        __syncthreads();
    }

    // ---- epilogue: + bias, fp32 store ----
    const int li = lane & 15, lq = lane >> 4;
#pragma unroll
    for (int ni = 0; ni < 4; ++ni) {
        const int c = col0 + wn * 64 + ni * 16 + li;
        const float bv = bias[c];
#pragma unroll
        for (int mi = 0; mi < 4; ++mi) {
#pragma unroll
            for (int r = 0; r < 4; ++r) {
                const int row = row0 + wm * 64 + mi * 16 + lq * 4 + r;
                if (row < M) out[(size_t)row * N + c] = acc[mi][ni][r] + bv;
            }
        }
    }
}

// ---------- CSR build ----------
__global__ void hist_k(const int* __restrict__ dst, int* __restrict__ deg, int E)
{
    const int e = blockIdx.x * blockDim.x + threadIdx.x;
    if (e < E) atomicAdd(&deg[dst[e]], 1);
}

__global__ void scan1_k(const int* __restrict__ deg, int* __restrict__ rowptr,
                        int* __restrict__ bsum, int N)
{
    __shared__ int buf[256];
    const int i = blockIdx.x * 256 + threadIdx.x;
    const int v = (i < N) ? deg[i] : 0;
    buf[threadIdx.x] = v;
    __syncthreads();
#pragma unroll
    for (int off = 1; off < 256; off <<= 1) {
        const int t = (threadIdx.x >= (unsigned)off) ? buf[threadIdx.x - off] : 0;
        __syncthreads();
        buf[threadIdx.x] += t;
        __syncthreads();
    }
    if (i < N) rowptr[i] = buf[threadIdx.x] - v;
    if (threadIdx.x == 255) bsum[blockIdx.x] = buf[255];
}

__global__ void scan2_k(int* __restrict__ bsum, int nb)
{
    __shared__ int buf[256];
    const int v = (threadIdx.x < (unsigned)nb) ? bsum[threadIdx.x] : 0;
    buf[threadIdx.x] = v;
    __syncthreads();
#pragma unroll
    for (int off = 1; off < 256; off <<= 1) {
        const int t = (threadIdx.x >= (unsigned)off) ? buf[threadIdx.x - off] : 0;
        __syncthreads();
        buf[threadIdx.x] += t;
        __syncthreads();
    }
    if (threadIdx.x < (unsigned)nb) bsum[threadIdx.x] = buf[threadIdx.x] - v;
}

__global__ void scan3_k(int* __restrict__ rowptr, const int* __restrict__ bsum,
                        int* __restrict__ cursor, int N, int E)
{
    const int i = blockIdx.x * 256 + threadIdx.x;
    if (i < N) {
        const int r = rowptr[i] + bsum[blockIdx.x];
        rowptr[i] = r;
        cursor[i] = r;
    }
    if (i == 0) rowptr[N] = E;
}

__global__ void scatter_k(const int* __restrict__ src, const int* __restrict__ dst,
                          int* __restrict__ cursor, int2* __restrict__ eord, int E)
{
    const int e = blockIdx.x * blockDim.x + threadIdx.x;
    if (e >= E) return;
    const int d = dst[e];
    const int p = atomicAdd(&cursor[d], 1);
    eord[p] = make_int2(e, src[e]);
}

// ---------- fused node-centric GATv2 ----------
template <int H>
__global__ __launch_bounds__(256, 4) void node_gat_k(
    const float* __restrict__ xl, const float* __restrict__ xr,
    const float* __restrict__ eattr, const float* __restrict__ We,
    const float* __restrict__ att, const float* __restrict__ bias,
    const int* __restrict__ rowptr, const int2* __restrict__ eord,
    float* __restrict__ out, int N)
{
    const int lane = threadIdx.x & 63;
    const int n = blockIdx.x * 4 + (threadIdx.x >> 6);
    if (n >= N) return;

    const int hc0 = (H == 4) ? (((lane >> 4) << 6) + ((lane & 15) << 2))
                             : (lane << 2);

    float we[8][4];
#pragma unroll
    for (int t = 0; t < 8; ++t) {
        const float4 v = *reinterpret_cast<const float4*>(&We[t * 256 + hc0]);
        we[t][0] = v.x; we[t][1] = v.y; we[t][2] = v.z; we[t][3] = v.w;
    }
    const float4 a4 = *reinterpret_cast<const float4*>(&att[hc0]);
    const float av[4] = {a4.x, a4.y, a4.z, a4.w};
    const float4 r4 = *reinterpret_cast<const float4*>(&xr[(size_t)n * 256 + hc0]);
    const float xrv[4] = {r4.x, r4.y, r4.z, r4.w};

    float acc[4] = {0.f, 0.f, 0.f, 0.f};
    float m = -INFINITY, den = 0.f;

    auto load_e = [&](const int2 es, float (&xv)[4], float (&ea)[8]) {
        const float4 x4 = *reinterpret_cast<const float4*>(
            &xl[(size_t)es.y * 256 + hc0]);
        xv[0] = x4.x; xv[1] = x4.y; xv[2] = x4.z; xv[3] = x4.w;
        const float4 e0 = *reinterpret_cast<const float4*>(&eattr[(size_t)es.x * 8]);
        const float4 e1 = *reinterpret_cast<const float4*>(&eattr[(size_t)es.x * 8 + 4]);
        ea[0] = e0.x; ea[1] = e0.y; ea[2] = e0.z; ea[3] = e0.w;
        ea[4] = e1.x; ea[5] = e1.y; ea[6] = e1.z; ea[7] = e1.w;
    };
    auto sc_of = [&](const float (&xv)[4], const float (&ea)[8]) -> float {
        float p = 0.f;
#pragma unroll
        for (int c = 0; c < 4; ++c) {
            float s = xv[c] + xrv[c];
#pragma unroll
            for (int t = 0; t < 8; ++t) s = fmaf(ea[t], we[t][c], s);
            s = fmaxf(s, LR_SLOPE * s);
            p = fmaf(s, av[c], p);
        }
#pragma unroll
        for (int off = 1; off < (H == 4 ? 16 : 64); off <<= 1)
            p += __shfl_xor(p, off, 64);
        return p;
    };

    const int k0 = rowptr[n], k1 = rowptr[n + 1];
    int k = k0;
    for (; k + 4 <= k1; k += 4) {
        const int2 es0 = eord[k],     es1 = eord[k + 1];
        const int2 es2 = eord[k + 2], es3 = eord[k + 3];
        float x0[4], x1[4], x2[4], x3[4];
        float ea0[8], ea1[8], ea2[8], ea3[8];
        load_e(es0, x0, ea0); load_e(es1, x1, ea1);
        load_e(es2, x2, ea2); load_e(es3, x3, ea3);
        const float s0 = sc_of(x0, ea0);
        const float s1 = sc_of(x1, ea1);
        const float s2 = sc_of(x2, ea2);
        const float s3 = sc_of(x3, ea3);
        const float nm = fmaxf(fmaxf(m, fmaxf(s0, s1)), fmaxf(s2, s3));
        const float sc = __expf(m - nm);
        const float w0 = __expf(s0 - nm), w1 = __expf(s1 - nm);
        const float w2 = __expf(s2 - nm), w3 = __expf(s3 - nm);
        den = fmaf(den, sc, (w0 + w1) + (w2 + w3));
#pragma unroll
        for (int c = 0; c < 4; ++c)
            acc[c] = fmaf(acc[c], sc,
                     fmaf(w0, x0[c], fmaf(w1, x1[c], fmaf(w2, x2[c], w3 * x3[c]))));
        m = nm;
    }
    for (; k < k1; ++k) {
        const int2 es0 = eord[k];
        float x0[4]; float ea0[8];
        load_e(es0, x0, ea0);
        const float s0 = sc_of(x0, ea0);
        const float nm = fmaxf(m, s0);
        const float sc = __expf(m - nm);
        const float w0 = __expf(s0 - nm);
        den = fmaf(den, sc, w0);
#pragma unroll
        for (int c = 0; c < 4; ++c)
            acc[c] = fmaf(acc[c], sc, w0 * x0[c]);
        m = nm;
    }

    const float inv = (den > 0.f) ? 1.f / den : 0.f;
    const float4 b4 = *reinterpret_cast<const float4*>(&bias[hc0]);
    float4 o;
    o.x = fmaxf(fmaf(acc[0], inv, b4.x), 0.f);
    o.y = fmaxf(fmaf(acc[1], inv, b4.y), 0.f);
    o.z = fmaxf(fmaf(acc[2], inv, b4.z), 0.f);
    o.w = fmaxf(fmaf(acc[3], inv, b4.w), 0.f);
    *reinterpret_cast<float4*>(&out[(size_t)n * 256 + hc0]) = o;
}

extern "C" void kernel_launch(void* const* d_in, const int* in_sizes, int n_in,
                              void* d_out, int out_size, void* d_ws, size_t ws_size,
                              hipStream_t stream)
{
    const float* x     = (const float*)d_in[0];
    const int*   eidx  = (const int*)d_in[1];
    const float* eattr = (const float*)d_in[2];
    const float* W1  = (const float*)d_in[3];
    const float* b1  = (const float*)d_in[4];
    const float* W2  = (const float*)d_in[5];
    const float* b2  = (const float*)d_in[6];
    const float* Wl1 = (const float*)d_in[7];
    const float* bl1 = (const float*)d_in[8];
    const float* Wr1 = (const float*)d_in[9];
    const float* br1 = (const float*)d_in[10];
    const float* We1 = (const float*)d_in[11];
    const float* att1 = (const float*)d_in[12];
    const float* bias1 = (const float*)d_in[13];
    const float* Wl2 = (const float*)d_in[14];
    const float* bl2 = (const float*)d_in[15];
    const float* Wr2 = (const float*)d_in[16];
    const float* br2 = (const float*)d_in[17];
    const float* We2 = (const float*)d_in[18];
    const float* att2 = (const float*)d_in[19];
    const float* bias2 = (const float*)d_in[20];

    const int N = in_sizes[0] / 32;        // 50000
    const int E = in_sizes[2] / 8;         // 800000
    const int* src = eidx;
    const int* dst = eidx + E;

    // ---- workspace layout ----
    auto align256 = [](size_t v) { return (v + 255) & ~(size_t)255; };
    char* ws = (char*)d_ws;
    size_t off = 0;
    float* h1 = (float*)(ws + off);    off += align256((size_t)N * 64 * 4);
    float* h2 = (float*)(ws + off);    off += align256((size_t)N * 64 * 4);
    float* xl = (float*)(ws + off);    off += align256((size_t)N * 256 * 4);
    float* xr = (float*)(ws + off);    off += align256((size_t)N * 256 * 4);
    float* out1 = (float*)(ws + off);  off += align256((size_t)N * 256 * 4);
    int* deg = (int*)(ws + off);       off += align256((size_t)N * 4);
    int* rowptr = (int*)(ws + off);    off += align256((size_t)(N + 1) * 4);
    int* cursor = (int*)(ws + off);    off += align256((size_t)N * 4);
    int* bsum = (int*)(ws + off);      off += align256((size_t)1024 * 4);
    int2* eord = (int2*)(ws + off);    off += align256((size_t)E * 8);
    short* wtl1 = (short*)(ws + off);  off += align256((size_t)256 * 64 * 2);
    short* wtr1 = (short*)(ws + off);  off += align256((size_t)256 * 64 * 2);
    short* wtl2 = (short*)(ws + off);  off += align256((size_t)256 * 256 * 2);
    short* wtr2 = (short*)(ws + off);  off += align256((size_t)256 * 256 * 2);
    (void)ws_size;

    float* outf = (float*)d_out;

    const int egrid1 = (E + 255) / 256;
    const int ngrid4 = (N + 3) / 4;
    const int nblk = (N + 255) / 256;

    // ---- weight transposes (bf16), once ----
    wtrans_k<<<(256 * 64 + 255) / 256, 256, 0, stream>>>(Wl1, wtl1, 64, 256);
    wtrans_k<<<(256 * 64 + 255) / 256, 256, 0, stream>>>(Wr1, wtr1, 64, 256);
    wtrans_k<<<(256 * 256 + 255) / 256, 256, 0, stream>>>(Wl2, wtl2, 256, 256);
    wtrans_k<<<(256 * 256 + 255) / 256, 256, 0, stream>>>(Wr2, wtr2, 256, 256);

    // ---- CSR build (shared by both GAT layers) ----
    hipMemsetAsync(deg, 0, (size_t)N * 4, stream);
    hist_k<<<egrid1, 256, 0, stream>>>(dst, deg, E);
    scan1_k<<<nblk, 256, 0, stream>>>(deg, rowptr, bsum, N);
    scan2_k<<<1, 256, 0, stream>>>(bsum, nblk);
    scan3_k<<<nblk, 256, 0, stream>>>(rowptr, bsum, cursor, N, E);
    scatter_k<<<egrid1, 256, 0, stream>>>(src, dst, cursor, eord, E);

    // ---- MLP encoder (fp32, small) ----
    {
        dim3 g1((N + 63) / 64, 1);
        gemm_bias_act<<<g1, 256, 0, stream>>>(x,  W1, b1, h1, N, 64, 32, 1);
        gemm_bias_act<<<g1, 256, 0, stream>>>(h1, W2, b2, h2, N, 64, 64, 1);
    }

    // ---- GAT layer 1 transforms (bf16 MFMA) + fused edge/softmax/agg ----
    {
        dim3 g((N + 127) / 128, 2, 2);
        gemm_mfma_dual<<<g, 256, 0, stream>>>(h2, wtl1, bl1, xl, wtr1, br1, xr,
                                              N, 256, 64);
    }
    node_gat_k<4><<<ngrid4, 256, 0, stream>>>(xl, xr, eattr, We1, att1, bias1,
                                              rowptr, eord, out1, N);

    // ---- GAT layer 2 transforms (bf16 MFMA) + fused edge/softmax/agg ----
    {
        dim3 g((N + 127) / 128, 2, 2);
        gemm_mfma_dual<<<g, 256, 0, stream>>>(out1, wtl2, bl2, xl, wtr2, br2, xr,
                                              N, 256, 256);
    }
    node_gat_k<1><<<ngrid4, 256, 0, stream>>>(xl, xr, eattr, We2, att2, bias2,
                                              rowptr, eord, outf, N);
}

// Round 6
// 535.790 us; speedup vs baseline: 4.9686x; 1.0095x over previous
//
#include <hip/hip_runtime.h>
#include <hip/hip_bf16.h>
#include <math.h>

#define LR_SLOPE 0.2f

typedef __attribute__((ext_vector_type(8))) short bf16x8;
typedef __attribute__((ext_vector_type(4))) float f32x4;

// fp32 -> bf16 round-to-nearest-even (bit trick)
__device__ __forceinline__ unsigned short f2bf(float f) {
    unsigned u = __float_as_uint(f);
    u = (u + 0x7FFFu + ((u >> 16) & 1u)) >> 16;
    return (unsigned short)u;
}

// ---------- small GEMM (MLP, N=64): out = act(A@W + bias) ----------
__global__ __launch_bounds__(256) void gemm_bias_act(
    const float* __restrict__ A, const float* __restrict__ W,
    const float* __restrict__ bias, float* __restrict__ out,
    int M, int N, int K, int do_relu)
{
    __shared__ float As[16][64];
    __shared__ float Ws[16][64];
    const int tid = threadIdx.x;
    const int tx = tid & 15;
    const int ty = tid >> 4;
    const int row0 = blockIdx.x * 64;
    const int col0 = blockIdx.y * 64;

    float acc[4][4] = {{0.f}};

    for (int kk = 0; kk < K; kk += 16) {
        {
            const int ra = tid >> 2;
            const int ka = (tid & 3) << 2;
            float4 v = make_float4(0.f, 0.f, 0.f, 0.f);
            const int r = row0 + ra;
            if (r < M)
                v = *reinterpret_cast<const float4*>(&A[(size_t)r * K + kk + ka]);
            As[ka + 0][ra] = v.x;
            As[ka + 1][ra] = v.y;
            As[ka + 2][ra] = v.z;
            As[ka + 3][ra] = v.w;
        }
        {
            const int rw = tid >> 4;
            const int cw = (tid & 15) << 2;
            float4 v = *reinterpret_cast<const float4*>(
                &W[(size_t)(kk + rw) * N + col0 + cw]);
            *reinterpret_cast<float4*>(&Ws[rw][cw]) = v;
        }
        __syncthreads();
#pragma unroll
        for (int k = 0; k < 16; ++k) {
            const float4 a = *reinterpret_cast<const float4*>(&As[k][ty * 4]);
            const float4 b = *reinterpret_cast<const float4*>(&Ws[k][tx * 4]);
            const float av[4] = {a.x, a.y, a.z, a.w};
            const float bv[4] = {b.x, b.y, b.z, b.w};
#pragma unroll
            for (int i = 0; i < 4; ++i)
#pragma unroll
                for (int j = 0; j < 4; ++j)
                    acc[i][j] += av[i] * bv[j];
        }
        __syncthreads();
    }

#pragma unroll
    for (int i = 0; i < 4; ++i) {
        const int r = row0 + ty * 4 + i;
        if (r >= M) continue;
#pragma unroll
        for (int j = 0; j < 4; ++j) {
            const int c = col0 + tx * 4 + j;
            float v = acc[i][j] + bias[c];
            if (do_relu) v = fmaxf(v, 0.f);
            out[(size_t)r * N + c] = v;
        }
    }
}

// ---------- all 4 weight transposes + bf16 convert in one launch ----------
// Wt[n][k] = bf16(W[k][n]).  Sizes: 2x (64x256), 2x (256x256).
__global__ void wtrans_all_k(
    const float* __restrict__ Wl1, const float* __restrict__ Wr1,
    const float* __restrict__ Wl2, const float* __restrict__ Wr2,
    short* __restrict__ o1, short* __restrict__ o2,
    short* __restrict__ o3, short* __restrict__ o4)
{
    const int i = blockIdx.x * 256 + threadIdx.x;
    const int S1 = 256 * 64, S2 = 256 * 256;
    if (i < S1) {                       // o1: Wl1
        const int n = i / 64, k = i % 64;
        o1[i] = (short)f2bf(Wl1[(size_t)k * 256 + n]);
    } else if (i < 2 * S1) {            // o2: Wr1
        const int j = i - S1;
        const int n = j / 64, k = j % 64;
        o2[j] = (short)f2bf(Wr1[(size_t)k * 256 + n]);
    } else if (i < 2 * S1 + S2) {       // o3: Wl2
        const int j = i - 2 * S1;
        const int n = j / 256, k = j % 256;
        o3[j] = (short)f2bf(Wl2[(size_t)k * 256 + n]);
    } else if (i < 2 * S1 + 2 * S2) {   // o4: Wr2
        const int j = i - 2 * S1 - S2;
        const int n = j / 256, k = j % 256;
        o4[j] = (short)f2bf(Wr2[(size_t)k * 256 + n]);
    }
}

// ---------- MFMA dual GEMM: {out0,out1} = A @ {W0,W1} + {b0,b1} ----------
__global__ __launch_bounds__(256) void gemm_mfma_dual(
    const float* __restrict__ A,
    const short* __restrict__ Wt0, const float* __restrict__ b0,
    float* __restrict__ out0,
    const short* __restrict__ Wt1, const float* __restrict__ b1,
    float* __restrict__ out1,
    int M, int N, int K)
{
    const short* __restrict__ Wt   = blockIdx.z ? Wt1 : Wt0;
    const float* __restrict__ bias = blockIdx.z ? b1 : b0;
    float* __restrict__ out        = blockIdx.z ? out1 : out0;

    __shared__ __align__(16) short As[4][128][8];
    __shared__ __align__(16) short Bs[4][128][8];

    const int tid = threadIdx.x;
    const int lane = tid & 63;
    const int wid = tid >> 6;
    const int wm = wid >> 1, wn = wid & 1;
    const int row0 = blockIdx.x * 128;
    const int col0 = blockIdx.y * 128;

    f32x4 acc[4][4] = {};

    const int srow = tid & 127;
    const int skg2 = tid >> 7;

    for (int kk = 0; kk < K; kk += 32) {
        {
            const int r = row0 + srow;
            float v[16];
            if (r < M) {
                const float4* p = reinterpret_cast<const float4*>(
                    &A[(size_t)r * K + kk + skg2 * 16]);
                *reinterpret_cast<float4*>(&v[0])  = p[0];
                *reinterpret_cast<float4*>(&v[4])  = p[1];
                *reinterpret_cast<float4*>(&v[8])  = p[2];
                *reinterpret_cast<float4*>(&v[12]) = p[3];
            } else {
#pragma unroll
                for (int j = 0; j < 16; ++j) v[j] = 0.f;
            }
            short s[16];
#pragma unroll
            for (int j = 0; j < 16; ++j) s[j] = (short)f2bf(v[j]);
            *reinterpret_cast<bf16x8*>(&As[skg2 * 2 + 0][srow][0]) =
                *reinterpret_cast<bf16x8*>(&s[0]);
            *reinterpret_cast<bf16x8*>(&As[skg2 * 2 + 1][srow][0]) =
                *reinterpret_cast<bf16x8*>(&s[8]);
        }
        {
            const float4* p = reinterpret_cast<const float4*>(
                &Wt[(size_t)(col0 + srow) * K + kk + skg2 * 16]);
            *reinterpret_cast<float4*>(&Bs[skg2 * 2 + 0][srow][0]) = p[0];
            *reinterpret_cast<float4*>(&Bs[skg2 * 2 + 1][srow][0]) = p[1];
        }
        __syncthreads();

        const int kg = lane >> 4, li = lane & 15;
        bf16x8 af[4], bfr[4];
#pragma unroll
        for (int mi = 0; mi < 4; ++mi)
            af[mi] = *reinterpret_cast<bf16x8*>(&As[kg][wm * 64 + mi * 16 + li][0]);
#pragma unroll
        for (int ni = 0; ni < 4; ++ni)
            bfr[ni] = *reinterpret_cast<bf16x8*>(&Bs[kg][wn * 64 + ni * 16 + li][0]);
#pragma unroll
        for (int mi = 0; mi < 4; ++mi)
#pragma unroll
            for (int ni = 0; ni < 4; ++ni)
                acc[mi][ni] = __builtin_amdgcn_mfma_f32_16x16x32_bf16(
                    af[mi], bfr[ni], acc[mi][ni], 0, 0, 0);
        __syncthreads();
    }

    const int li = lane & 15, lq = lane >> 4;
#pragma unroll
    for (int ni = 0; ni < 4; ++ni) {
        const int c = col0 + wn * 64 + ni * 16 + li;
        const float bv = bias[c];
#pragma unroll
        for (int mi = 0; mi < 4; ++mi) {
#pragma unroll
            for (int r = 0; r < 4; ++r) {
                const int row = row0 + wm * 64 + mi * 16 + lq * 4 + r;
                if (row < M) out[(size_t)row * N + c] = acc[mi][ni][r] + bv;
            }
        }
    }
}

// ---------- CSR build ----------
__global__ void hist_k(const int* __restrict__ dst, int* __restrict__ deg, int E)
{
    const int e = blockIdx.x * blockDim.x + threadIdx.x;
    if (e < E) atomicAdd(&deg[dst[e]], 1);
}

__global__ void scan1_k(const int* __restrict__ deg, int* __restrict__ rowptr,
                        int* __restrict__ bsum, int N)
{
    __shared__ int buf[256];
    const int i = blockIdx.x * 256 + threadIdx.x;
    const int v = (i < N) ? deg[i] : 0;
    buf[threadIdx.x] = v;
    __syncthreads();
#pragma unroll
    for (int off = 1; off < 256; off <<= 1) {
        const int t = (threadIdx.x >= (unsigned)off) ? buf[threadIdx.x - off] : 0;
        __syncthreads();
        buf[threadIdx.x] += t;
        __syncthreads();
    }
    if (i < N) rowptr[i] = buf[threadIdx.x] - v;
    if (threadIdx.x == 255) bsum[blockIdx.x] = buf[255];
}

__global__ void scan2_k(int* __restrict__ bsum, int nb)
{
    __shared__ int buf[256];
    const int v = (threadIdx.x < (unsigned)nb) ? bsum[threadIdx.x] : 0;
    buf[threadIdx.x] = v;
    __syncthreads();
#pragma unroll
    for (int off = 1; off < 256; off <<= 1) {
        const int t = (threadIdx.x >= (unsigned)off) ? buf[threadIdx.x - off] : 0;
        __syncthreads();
        buf[threadIdx.x] += t;
        __syncthreads();
    }
    if (threadIdx.x < (unsigned)nb) bsum[threadIdx.x] = buf[threadIdx.x] - v;
}

__global__ void scan3_k(int* __restrict__ rowptr, const int* __restrict__ bsum,
                        int* __restrict__ cursor, int N, int E)
{
    const int i = blockIdx.x * 256 + threadIdx.x;
    if (i < N) {
        const int r = rowptr[i] + bsum[blockIdx.x];
        rowptr[i] = r;
        cursor[i] = r;
    }
    if (i == 0) rowptr[N] = E;
}

// scatter src AND the eattr payload into dst-sorted order (streaming reads later)
__global__ void scatter_k(const int* __restrict__ src, const int* __restrict__ dst,
                          const float4* __restrict__ eattr,
                          int* __restrict__ cursor,
                          int* __restrict__ ssrc, float4* __restrict__ ea_s, int E)
{
    const int e = blockIdx.x * blockDim.x + threadIdx.x;
    if (e >= E) return;
    const int d = dst[e];
    const int p = atomicAdd(&cursor[d], 1);
    ssrc[p] = src[e];
    const float4 e0 = eattr[2 * e];
    const float4 e1 = eattr[2 * e + 1];
    ea_s[2 * p] = e0;
    ea_s[2 * p + 1] = e1;
}

// ---------- fused node-centric GATv2 ----------
// NPW nodes per wave; We/att/bias live in registers across nodes.
// Lane owns 4 contiguous channels of one head:
//   H=4: head = lane>>4, hc0 = head*64 + (lane&15)*4  (4-step reduce)
//   H=1: hc0 = lane*4                                  (6-step reduce)
template <int H, int NPW>
__global__ __launch_bounds__(256, 4) void node_gat_k(
    const float* __restrict__ xl, const float* __restrict__ xr,
    const float4* __restrict__ ea_s, const int* __restrict__ ssrc,
    const float* __restrict__ We, const float* __restrict__ att,
    const float* __restrict__ bias,
    const int* __restrict__ rowptr, float* __restrict__ out, int N)
{
    const int lane = threadIdx.x & 63;
    const int nbase = (blockIdx.x * 4 + (threadIdx.x >> 6)) * NPW;
    if (nbase >= N) return;

    const int hc0 = (H == 4) ? (((lane >> 4) << 6) + ((lane & 15) << 2))
                             : (lane << 2);

    float we[8][4];
#pragma unroll
    for (int t = 0; t < 8; ++t) {
        const float4 v = *reinterpret_cast<const float4*>(&We[t * 256 + hc0]);
        we[t][0] = v.x; we[t][1] = v.y; we[t][2] = v.z; we[t][3] = v.w;
    }
    const float4 a4 = *reinterpret_cast<const float4*>(&att[hc0]);
    const float av[4] = {a4.x, a4.y, a4.z, a4.w};
    const float4 b4 = *reinterpret_cast<const float4*>(&bias[hc0]);

    for (int ni = 0; ni < NPW; ++ni) {
        const int n = nbase + ni;
        if (n >= N) return;
        const float4 r4 = *reinterpret_cast<const float4*>(
            &xr[(unsigned)((n << 8) + hc0)]);
        const float xrv[4] = {r4.x, r4.y, r4.z, r4.w};

        float acc[4] = {0.f, 0.f, 0.f, 0.f};
        float m = -INFINITY, den = 0.f;

        auto load_e = [&](const int k, float (&xv)[4], float (&ea)[8]) {
            const int sv = ssrc[k];
            const float4 x4 = *reinterpret_cast<const float4*>(
                &xl[(unsigned)((sv << 8) + hc0)]);
            xv[0] = x4.x; xv[1] = x4.y; xv[2] = x4.z; xv[3] = x4.w;
            const float4 e0 = ea_s[2 * k];
            const float4 e1 = ea_s[2 * k + 1];
            ea[0] = e0.x; ea[1] = e0.y; ea[2] = e0.z; ea[3] = e0.w;
            ea[4] = e1.x; ea[5] = e1.y; ea[6] = e1.z; ea[7] = e1.w;
        };
        auto sc_of = [&](const float (&xv)[4], const float (&ea)[8]) -> float {
            float p = 0.f;
#pragma unroll
            for (int c = 0; c < 4; ++c) {
                float s = xv[c] + xrv[c];
#pragma unroll
                for (int t = 0; t < 8; ++t) s = fmaf(ea[t], we[t][c], s);
                s = fmaxf(s, LR_SLOPE * s);
                p = fmaf(s, av[c], p);
            }
#pragma unroll
            for (int off = 1; off < (H == 4 ? 16 : 64); off <<= 1)
                p += __shfl_xor(p, off, 64);
            return p;
        };

        const int k0 = rowptr[n], k1 = rowptr[n + 1];
        int k = k0;
        for (; k + 4 <= k1; k += 4) {
            float x0[4], x1[4], x2[4], x3[4];
            float ea0[8], ea1[8], ea2[8], ea3[8];
            load_e(k, x0, ea0);     load_e(k + 1, x1, ea1);
            load_e(k + 2, x2, ea2); load_e(k + 3, x3, ea3);
            const float s0 = sc_of(x0, ea0);
            const float s1 = sc_of(x1, ea1);
            const float s2 = sc_of(x2, ea2);
            const float s3 = sc_of(x3, ea3);
            const float nm = fmaxf(fmaxf(m, fmaxf(s0, s1)), fmaxf(s2, s3));
            const float sc = __expf(m - nm);
            const float w0 = __expf(s0 - nm), w1 = __expf(s1 - nm);
            const float w2 = __expf(s2 - nm), w3 = __expf(s3 - nm);
            den = fmaf(den, sc, (w0 + w1) + (w2 + w3));
#pragma unroll
            for (int c = 0; c < 4; ++c)
                acc[c] = fmaf(acc[c], sc,
                         fmaf(w0, x0[c], fmaf(w1, x1[c], fmaf(w2, x2[c], w3 * x3[c]))));
            m = nm;
        }
        for (; k < k1; ++k) {
            float x0[4]; float ea0[8];
            load_e(k, x0, ea0);
            const float s0 = sc_of(x0, ea0);
            const float nm = fmaxf(m, s0);
            const float sc = __expf(m - nm);
            const float w0 = __expf(s0 - nm);
            den = fmaf(den, sc, w0);
#pragma unroll
            for (int c = 0; c < 4; ++c)
                acc[c] = fmaf(acc[c], sc, w0 * x0[c]);
            m = nm;
        }

        const float inv = (den > 0.f) ? 1.f / den : 0.f;
        float4 o;
        o.x = fmaxf(fmaf(acc[0], inv, b4.x), 0.f);
        o.y = fmaxf(fmaf(acc[1], inv, b4.y), 0.f);
        o.z = fmaxf(fmaf(acc[2], inv, b4.z), 0.f);
        o.w = fmaxf(fmaf(acc[3], inv, b4.w), 0.f);
        *reinterpret_cast<float4*>(&out[(unsigned)((n << 8) + hc0)]) = o;
    }
}

extern "C" void kernel_launch(void* const* d_in, const int* in_sizes, int n_in,
                              void* d_out, int out_size, void* d_ws, size_t ws_size,
                              hipStream_t stream)
{
    const float* x     = (const float*)d_in[0];
    const int*   eidx  = (const int*)d_in[1];
    const float* eattr = (const float*)d_in[2];
    const float* W1  = (const float*)d_in[3];
    const float* b1  = (const float*)d_in[4];
    const float* W2  = (const float*)d_in[5];
    const float* b2  = (const float*)d_in[6];
    const float* Wl1 = (const float*)d_in[7];
    const float* bl1 = (const float*)d_in[8];
    const float* Wr1 = (const float*)d_in[9];
    const float* br1 = (const float*)d_in[10];
    const float* We1 = (const float*)d_in[11];
    const float* att1 = (const float*)d_in[12];
    const float* bias1 = (const float*)d_in[13];
    const float* Wl2 = (const float*)d_in[14];
    const float* bl2 = (const float*)d_in[15];
    const float* Wr2 = (const float*)d_in[16];
    const float* br2 = (const float*)d_in[17];
    const float* We2 = (const float*)d_in[18];
    const float* att2 = (const float*)d_in[19];
    const float* bias2 = (const float*)d_in[20];

    const int N = in_sizes[0] / 32;        // 50000
    const int E = in_sizes[2] / 8;         // 800000
    const int* src = eidx;
    const int* dst = eidx + E;

    // ---- workspace layout (ea_s aliases h1+h2: both dead before CSR build) ----
    auto align256 = [](size_t v) { return (v + 255) & ~(size_t)255; };
    char* ws = (char*)d_ws;
    size_t off = 0;
    float* h1 = (float*)(ws + off);    off += align256((size_t)N * 64 * 4);
    float* h2 = (float*)(ws + off);    off += align256((size_t)N * 64 * 4);
    float4* ea_s = (float4*)h1;        // E*32B == N*128*4B exactly (25.6 MB)
    float* xl = (float*)(ws + off);    off += align256((size_t)N * 256 * 4);
    float* xr = (float*)(ws + off);    off += align256((size_t)N * 256 * 4);
    float* out1 = (float*)(ws + off);  off += align256((size_t)N * 256 * 4);
    int* deg = (int*)(ws + off);       off += align256((size_t)N * 4);
    int* rowptr = (int*)(ws + off);    off += align256((size_t)(N + 1) * 4);
    int* cursor = (int*)(ws + off);    off += align256((size_t)N * 4);
    int* bsum = (int*)(ws + off);      off += align256((size_t)1024 * 4);
    int* ssrc = (int*)(ws + off);      off += align256((size_t)E * 4);
    short* wtl1 = (short*)(ws + off);  off += align256((size_t)256 * 64 * 2);
    short* wtr1 = (short*)(ws + off);  off += align256((size_t)256 * 64 * 2);
    short* wtl2 = (short*)(ws + off);  off += align256((size_t)256 * 256 * 2);
    short* wtr2 = (short*)(ws + off);  off += align256((size_t)256 * 256 * 2);
    (void)ws_size;

    float* outf = (float*)d_out;

    const int egrid1 = (E + 255) / 256;
    const int nblk = (N + 255) / 256;
    const int NPW = 4;
    const int ngat = (N + 4 * NPW - 1) / (4 * NPW);   // 3125 blocks

    // ---- weight transposes (bf16), one launch ----
    wtrans_all_k<<<(2 * 256 * 64 + 2 * 256 * 256 + 255) / 256, 256, 0, stream>>>(
        Wl1, Wr1, Wl2, Wr2, wtl1, wtr1, wtl2, wtr2);

    // ---- MLP encoder ----
    {
        dim3 g1((N + 63) / 64, 1);
        gemm_bias_act<<<g1, 256, 0, stream>>>(x,  W1, b1, h1, N, 64, 32, 1);
        gemm_bias_act<<<g1, 256, 0, stream>>>(h1, W2, b2, h2, N, 64, 64, 1);
    }

    // ---- GAT layer 1 transforms (bf16 MFMA): h2 -> xl, xr ----
    {
        dim3 g((N + 127) / 128, 2, 2);
        gemm_mfma_dual<<<g, 256, 0, stream>>>(h2, wtl1, bl1, xl, wtr1, br1, xr,
                                              N, 256, 64);
    }

    // ---- CSR build (h1/h2 now dead; ea_s reuses their space) ----
    hipMemsetAsync(deg, 0, (size_t)N * 4, stream);
    hist_k<<<egrid1, 256, 0, stream>>>(dst, deg, E);
    scan1_k<<<nblk, 256, 0, stream>>>(deg, rowptr, bsum, N);
    scan2_k<<<1, 256, 0, stream>>>(bsum, nblk);
    scan3_k<<<nblk, 256, 0, stream>>>(rowptr, bsum, cursor, N, E);
    scatter_k<<<egrid1, 256, 0, stream>>>(src, dst, (const float4*)eattr,
                                          cursor, ssrc, ea_s, E);

    // ---- GAT layer 1 fused edge/softmax/agg ----
    node_gat_k<4, NPW><<<ngat, 256, 0, stream>>>(xl, xr, ea_s, ssrc,
                                                 We1, att1, bias1,
                                                 rowptr, out1, N);

    // ---- GAT layer 2 transforms (bf16 MFMA): out1 -> xl, xr ----
    {
        dim3 g((N + 127) / 128, 2, 2);
        gemm_mfma_dual<<<g, 256, 0, stream>>>(out1, wtl2, bl2, xl, wtr2, br2, xr,
                                              N, 256, 256);
    }

    // ---- GAT layer 2 fused edge/softmax/agg ----
    node_gat_k<1, NPW><<<ngat, 256, 0, stream>>>(xl, xr, ea_s, ssrc,
                                                 We2, att2, bias2,
                                                 rowptr, outf, N);
}

// Round 7
// 533.945 us; speedup vs baseline: 4.9858x; 1.0035x over previous
//
#include <hip/hip_runtime.h>
#include <hip/hip_bf16.h>
#include <math.h>

#define LR_SLOPE 0.2f

typedef __attribute__((ext_vector_type(8))) short bf16x8;
typedef __attribute__((ext_vector_type(4))) float f32x4;

// fp32 -> bf16 round-to-nearest-even (bit trick)
__device__ __forceinline__ unsigned short f2bf(float f) {
    unsigned u = __float_as_uint(f);
    u = (u + 0x7FFFu + ((u >> 16) & 1u)) >> 16;
    return (unsigned short)u;
}

// ---------- small GEMM (MLP, N=64): out = act(A@W + bias) ----------
__global__ __launch_bounds__(256) void gemm_bias_act(
    const float* __restrict__ A, const float* __restrict__ W,
    const float* __restrict__ bias, float* __restrict__ out,
    int M, int N, int K, int do_relu)
{
    __shared__ float As[16][64];
    __shared__ float Ws[16][64];
    const int tid = threadIdx.x;
    const int tx = tid & 15;
    const int ty = tid >> 4;
    const int row0 = blockIdx.x * 64;
    const int col0 = blockIdx.y * 64;

    float acc[4][4] = {{0.f}};

    for (int kk = 0; kk < K; kk += 16) {
        {
            const int ra = tid >> 2;
            const int ka = (tid & 3) << 2;
            float4 v = make_float4(0.f, 0.f, 0.f, 0.f);
            const int r = row0 + ra;
            if (r < M)
                v = *reinterpret_cast<const float4*>(&A[(size_t)r * K + kk + ka]);
            As[ka + 0][ra] = v.x;
            As[ka + 1][ra] = v.y;
            As[ka + 2][ra] = v.z;
            As[ka + 3][ra] = v.w;
        }
        {
            const int rw = tid >> 4;
            const int cw = (tid & 15) << 2;
            float4 v = *reinterpret_cast<const float4*>(
                &W[(size_t)(kk + rw) * N + col0 + cw]);
            *reinterpret_cast<float4*>(&Ws[rw][cw]) = v;
        }
        __syncthreads();
#pragma unroll
        for (int k = 0; k < 16; ++k) {
            const float4 a = *reinterpret_cast<const float4*>(&As[k][ty * 4]);
            const float4 b = *reinterpret_cast<const float4*>(&Ws[k][tx * 4]);
            const float av[4] = {a.x, a.y, a.z, a.w};
            const float bv[4] = {b.x, b.y, b.z, b.w};
#pragma unroll
            for (int i = 0; i < 4; ++i)
#pragma unroll
                for (int j = 0; j < 4; ++j)
                    acc[i][j] += av[i] * bv[j];
        }
        __syncthreads();
    }

#pragma unroll
    for (int i = 0; i < 4; ++i) {
        const int r = row0 + ty * 4 + i;
        if (r >= M) continue;
#pragma unroll
        for (int j = 0; j < 4; ++j) {
            const int c = col0 + tx * 4 + j;
            float v = acc[i][j] + bias[c];
            if (do_relu) v = fmaxf(v, 0.f);
            out[(size_t)r * N + c] = v;
        }
    }
}

// ---------- all 4 weight transposes + bf16 convert in one launch ----------
// Wt[n][k] = bf16(W[k][n]).  Sizes: 2x (64x256), 2x (256x256).
__global__ void wtrans_all_k(
    const float* __restrict__ Wl1, const float* __restrict__ Wr1,
    const float* __restrict__ Wl2, const float* __restrict__ Wr2,
    short* __restrict__ o1, short* __restrict__ o2,
    short* __restrict__ o3, short* __restrict__ o4)
{
    const int i = blockIdx.x * 256 + threadIdx.x;
    const int S1 = 256 * 64, S2 = 256 * 256;
    if (i < S1) {                       // o1: Wl1
        const int n = i / 64, k = i % 64;
        o1[i] = (short)f2bf(Wl1[(size_t)k * 256 + n]);
    } else if (i < 2 * S1) {            // o2: Wr1
        const int j = i - S1;
        const int n = j / 64, k = j % 64;
        o2[j] = (short)f2bf(Wr1[(size_t)k * 256 + n]);
    } else if (i < 2 * S1 + S2) {       // o3: Wl2
        const int j = i - 2 * S1;
        const int n = j / 256, k = j % 256;
        o3[j] = (short)f2bf(Wl2[(size_t)k * 256 + n]);
    } else if (i < 2 * S1 + 2 * S2) {   // o4: Wr2
        const int j = i - 2 * S1 - S2;
        const int n = j / 256, k = j % 256;
        o4[j] = (short)f2bf(Wr2[(size_t)k * 256 + n]);
    }
}

// ---------- MFMA dual GEMM: {out0,out1} = A @ {W0,W1} + {b0,b1} ----------
__global__ __launch_bounds__(256) void gemm_mfma_dual(
    const float* __restrict__ A,
    const short* __restrict__ Wt0, const float* __restrict__ b0,
    float* __restrict__ out0,
    const short* __restrict__ Wt1, const float* __restrict__ b1,
    float* __restrict__ out1,
    int M, int N, int K)
{
    const short* __restrict__ Wt   = blockIdx.z ? Wt1 : Wt0;
    const float* __restrict__ bias = blockIdx.z ? b1 : b0;
    float* __restrict__ out        = blockIdx.z ? out1 : out0;

    __shared__ __align__(16) short As[4][128][8];
    __shared__ __align__(16) short Bs[4][128][8];

    const int tid = threadIdx.x;
    const int lane = tid & 63;
    const int wid = tid >> 6;
    const int wm = wid >> 1, wn = wid & 1;
    const int row0 = blockIdx.x * 128;
    const int col0 = blockIdx.y * 128;

    f32x4 acc[4][4] = {};

    const int srow = tid & 127;
    const int skg2 = tid >> 7;

    for (int kk = 0; kk < K; kk += 32) {
        {
            const int r = row0 + srow;
            float v[16];
            if (r < M) {
                const float4* p = reinterpret_cast<const float4*>(
                    &A[(size_t)r * K + kk + skg2 * 16]);
                *reinterpret_cast<float4*>(&v[0])  = p[0];
                *reinterpret_cast<float4*>(&v[4])  = p[1];
                *reinterpret_cast<float4*>(&v[8])  = p[2];
                *reinterpret_cast<float4*>(&v[12]) = p[3];
            } else {
#pragma unroll
                for (int j = 0; j < 16; ++j) v[j] = 0.f;
            }
            short s[16];
#pragma unroll
            for (int j = 0; j < 16; ++j) s[j] = (short)f2bf(v[j]);
            *reinterpret_cast<bf16x8*>(&As[skg2 * 2 + 0][srow][0]) =
                *reinterpret_cast<bf16x8*>(&s[0]);
            *reinterpret_cast<bf16x8*>(&As[skg2 * 2 + 1][srow][0]) =
                *reinterpret_cast<bf16x8*>(&s[8]);
        }
        {
            const float4* p = reinterpret_cast<const float4*>(
                &Wt[(size_t)(col0 + srow) * K + kk + skg2 * 16]);
            *reinterpret_cast<float4*>(&Bs[skg2 * 2 + 0][srow][0]) = p[0];
            *reinterpret_cast<float4*>(&Bs[skg2 * 2 + 1][srow][0]) = p[1];
        }
        __syncthreads();

        const int kg = lane >> 4, li = lane & 15;
        bf16x8 af[4], bfr[4];
#pragma unroll
        for (int mi = 0; mi < 4; ++mi)
            af[mi] = *reinterpret_cast<bf16x8*>(&As[kg][wm * 64 + mi * 16 + li][0]);
#pragma unroll
        for (int ni = 0; ni < 4; ++ni)
            bfr[ni] = *reinterpret_cast<bf16x8*>(&Bs[kg][wn * 64 + ni * 16 + li][0]);
#pragma unroll
        for (int mi = 0; mi < 4; ++mi)
#pragma unroll
            for (int ni = 0; ni < 4; ++ni)
                acc[mi][ni] = __builtin_amdgcn_mfma_f32_16x16x32_bf16(
                    af[mi], bfr[ni], acc[mi][ni], 0, 0, 0);
        __syncthreads();
    }

    const int li = lane & 15, lq = lane >> 4;
#pragma unroll
    for (int ni = 0; ni < 4; ++ni) {
        const int c = col0 + wn * 64 + ni * 16 + li;
        const float bv = bias[c];
#pragma unroll
        for (int mi = 0; mi < 4; ++mi) {
#pragma unroll
            for (int r = 0; r < 4; ++r) {
                const int row = row0 + wm * 64 + mi * 16 + lq * 4 + r;
                if (row < M) out[(size_t)row * N + c] = acc[mi][ni][r] + bv;
            }
        }
    }
}

// ---------- CSR build ----------
__global__ void hist_k(const int* __restrict__ dst, int* __restrict__ deg, int E)
{
    const int e = blockIdx.x * blockDim.x + threadIdx.x;
    if (e < E) atomicAdd(&deg[dst[e]], 1);
}

__global__ void scan1_k(const int* __restrict__ deg, int* __restrict__ rowptr,
                        int* __restrict__ bsum, int N)
{
    __shared__ int buf[256];
    const int i = blockIdx.x * 256 + threadIdx.x;
    const int v = (i < N) ? deg[i] : 0;
    buf[threadIdx.x] = v;
    __syncthreads();
#pragma unroll
    for (int off = 1; off < 256; off <<= 1) {
        const int t = (threadIdx.x >= (unsigned)off) ? buf[threadIdx.x - off] : 0;
        __syncthreads();
        buf[threadIdx.x] += t;
        __syncthreads();
    }
    if (i < N) rowptr[i] = buf[threadIdx.x] - v;
    if (threadIdx.x == 255) bsum[blockIdx.x] = buf[255];
}

__global__ void scan2_k(int* __restrict__ bsum, int nb)
{
    __shared__ int buf[256];
    const int v = (threadIdx.x < (unsigned)nb) ? bsum[threadIdx.x] : 0;
    buf[threadIdx.x] = v;
    __syncthreads();
#pragma unroll
    for (int off = 1; off < 256; off <<= 1) {
        const int t = (threadIdx.x >= (unsigned)off) ? buf[threadIdx.x - off] : 0;
        __syncthreads();
        buf[threadIdx.x] += t;
        __syncthreads();
    }
    if (threadIdx.x < (unsigned)nb) bsum[threadIdx.x] = buf[threadIdx.x] - v;
}

__global__ void scan3_k(int* __restrict__ rowptr, const int* __restrict__ bsum,
                        int* __restrict__ cursor, int N, int E)
{
    const int i = blockIdx.x * 256 + threadIdx.x;
    if (i < N) {
        const int r = rowptr[i] + bsum[blockIdx.x];
        rowptr[i] = r;
        cursor[i] = r;
    }
    if (i == 0) rowptr[N] = E;
}

// scatter src AND the eattr payload into dst-sorted order (streaming reads later)
__global__ void scatter_k(const int* __restrict__ src, const int* __restrict__ dst,
                          const float4* __restrict__ eattr,
                          int* __restrict__ cursor,
                          int* __restrict__ ssrc, float4* __restrict__ ea_s, int E)
{
    const int e = blockIdx.x * blockDim.x + threadIdx.x;
    if (e >= E) return;
    const int d = dst[e];
    const int p = atomicAdd(&cursor[d], 1);
    ssrc[p] = src[e];
    const float4 e0 = eattr[2 * e];
    const float4 e1 = eattr[2 * e + 1];
    ea_s[2 * p] = e0;
    ea_s[2 * p + 1] = e1;
}

// ---------- fused node-centric GATv2 ----------
// NPW nodes per wave; We/att/bias live in registers across nodes.
// Lane owns 4 contiguous channels of one head:
//   H=4: head = lane>>4, hc0 = head*64 + (lane&15)*4  (4-step reduce)
//   H=1: hc0 = lane*4                                  (6-step reduce)
template <int H, int NPW>
__global__ __launch_bounds__(256, 4) void node_gat_k(
    const float* __restrict__ xl, const float* __restrict__ xr,
    const float4* __restrict__ ea_s, const int* __restrict__ ssrc,
    const float* __restrict__ We, const float* __restrict__ att,
    const float* __restrict__ bias,
    const int* __restrict__ rowptr, float* __restrict__ out, int N)
{
    const int lane = threadIdx.x & 63;
    const int nbase = (blockIdx.x * 4 + (threadIdx.x >> 6)) * NPW;
    if (nbase >= N) return;

    const int hc0 = (H == 4) ? (((lane >> 4) << 6) + ((lane & 15) << 2))
                             : (lane << 2);

    float we[8][4];
#pragma unroll
    for (int t = 0; t < 8; ++t) {
        const float4 v = *reinterpret_cast<const float4*>(&We[t * 256 + hc0]);
        we[t][0] = v.x; we[t][1] = v.y; we[t][2] = v.z; we[t][3] = v.w;
    }
    const float4 a4 = *reinterpret_cast<const float4*>(&att[hc0]);
    const float av[4] = {a4.x, a4.y, a4.z, a4.w};
    const float4 b4 = *reinterpret_cast<const float4*>(&bias[hc0]);

    for (int ni = 0; ni < NPW; ++ni) {
        const int n = nbase + ni;
        if (n >= N) return;
        const float4 r4 = *reinterpret_cast<const float4*>(
            &xr[(unsigned)((n << 8) + hc0)]);
        const float xrv[4] = {r4.x, r4.y, r4.z, r4.w};

        float acc[4] = {0.f, 0.f, 0.f, 0.f};
        float m = -INFINITY, den = 0.f;

        auto load_e = [&](const int k, float (&xv)[4], float (&ea)[8]) {
            const int sv = ssrc[k];
            const float4 x4 = *reinterpret_cast<const float4*>(
                &xl[(unsigned)((sv << 8) + hc0)]);
            xv[0] = x4.x; xv[1] = x4.y; xv[2] = x4.z; xv[3] = x4.w;
            const float4 e0 = ea_s[2 * k];
            const float4 e1 = ea_s[2 * k + 1];
            ea[0] = e0.x; ea[1] = e0.y; ea[2] = e0.z; ea[3] = e0.w;
            ea[4] = e1.x; ea[5] = e1.y; ea[6] = e1.z; ea[7] = e1.w;
        };
        auto sc_of = [&](const float (&xv)[4], const float (&ea)[8]) -> float {
            float p = 0.f;
#pragma unroll
            for (int c = 0; c < 4; ++c) {
                float s = xv[c] + xrv[c];
#pragma unroll
                for (int t = 0; t < 8; ++t) s = fmaf(ea[t], we[t][c], s);
                s = fmaxf(s, LR_SLOPE * s);
                p = fmaf(s, av[c], p);
            }
#pragma unroll
            for (int off = 1; off < (H == 4 ? 16 : 64); off <<= 1)
                p += __shfl_xor(p, off, 64);
            return p;
        };

        const int k0 = rowptr[n], k1 = rowptr[n + 1];
        int k = k0;
        for (; k + 4 <= k1; k += 4) {
            float x0[4], x1[4], x2[4], x3[4];
            float ea0[8], ea1[8], ea2[8], ea3[8];
            load_e(k, x0, ea0);     load_e(k + 1, x1, ea1);
            load_e(k + 2, x2, ea2); load_e(k + 3, x3, ea3);
            const float s0 = sc_of(x0, ea0);
            const float s1 = sc_of(x1, ea1);
            const float s2 = sc_of(x2, ea2);
            const float s3 = sc_of(x3, ea3);
            const float nm = fmaxf(fmaxf(m, fmaxf(s0, s1)), fmaxf(s2, s3));
            const float sc = __expf(m - nm);
            const float w0 = __expf(s0 - nm), w1 = __expf(s1 - nm);
            const float w2 = __expf(s2 - nm), w3 = __expf(s3 - nm);
            den = fmaf(den, sc, (w0 + w1) + (w2 + w3));
#pragma unroll
            for (int c = 0; c < 4; ++c)
                acc[c] = fmaf(acc[c], sc,
                         fmaf(w0, x0[c], fmaf(w1, x1[c], fmaf(w2, x2[c], w3 * x3[c]))));
            m = nm;
        }
        for (; k < k1; ++k) {
            float x0[4]; float ea0[8];
            load_e(k, x0, ea0);
            const float s0 = sc_of(x0, ea0);
            const float nm = fmaxf(m, s0);
            const float sc = __expf(m - nm);
            const float w0 = __expf(s0 - nm);
            den = fmaf(den, sc, w0);
#pragma unroll
            for (int c = 0; c < 4; ++c)
                acc[c] = fmaf(acc[c], sc, w0 * x0[c]);
            m = nm;
        }

        const float inv = (den > 0.f) ? 1.f / den : 0.f;
        float4 o;
        o.x = fmaxf(fmaf(acc[0], inv, b4.x), 0.f);
        o.y = fmaxf(fmaf(acc[1], inv, b4.y), 0.f);
        o.z = fmaxf(fmaf(acc[2], inv, b4.z), 0.f);
        o.w = fmaxf(fmaf(acc[3], inv, b4.w), 0.f);
        *reinterpret_cast<float4*>(&out[(unsigned)((n << 8) + hc0)]) = o;
    }
}

extern "C" void kernel_launch(void* const* d_in, const int* in_sizes, int n_in,
                              void* d_out, int out_size, void* d_ws, size_t ws_size,
                              hipStream_t stream)
{
    const float* x     = (const float*)d_in[0];
    const int*   eidx  = (const int*)d_in[1];
    const float* eattr = (const float*)d_in[2];
    const float* W1  = (const float*)d_in[3];
    const float* b1  = (const float*)d_in[4];
    const float* W2  = (const float*)d_in[5];
    const float* b2  = (const float*)d_in[6];
    const float* Wl1 = (const float*)d_in[7];
    const float* bl1 = (const float*)d_in[8];
    const float* Wr1 = (const float*)d_in[9];
    const float* br1 = (const float*)d_in[10];
    const float* We1 = (const float*)d_in[11];
    const float* att1 = (const float*)d_in[12];
    const float* bias1 = (const float*)d_in[13];
    const float* Wl2 = (const float*)d_in[14];
    const float* bl2 = (const float*)d_in[15];
    const float* Wr2 = (const float*)d_in[16];
    const float* br2 = (const float*)d_in[17];
    const float* We2 = (const float*)d_in[18];
    const float* att2 = (const float*)d_in[19];
    const float* bias2 = (const float*)d_in[20];

    const int N = in_sizes[0] / 32;        // 50000
    const int E = in_sizes[2] / 8;         // 800000
    const int* src = eidx;
    const int* dst = eidx + E;

    // ---- workspace layout (ea_s aliases h1+h2: both dead before CSR build) ----
    auto align256 = [](size_t v) { return (v + 255) & ~(size_t)255; };
    char* ws = (char*)d_ws;
    size_t off = 0;
    float* h1 = (float*)(ws + off);    off += align256((size_t)N * 64 * 4);
    float* h2 = (float*)(ws + off);    off += align256((size_t)N * 64 * 4);
    float4* ea_s = (float4*)h1;        // E*32B == N*128*4B exactly (25.6 MB)
    float* xl = (float*)(ws + off);    off += align256((size_t)N * 256 * 4);
    float* xr = (float*)(ws + off);    off += align256((size_t)N * 256 * 4);
    float* out1 = (float*)(ws + off);  off += align256((size_t)N * 256 * 4);
    int* deg = (int*)(ws + off);       off += align256((size_t)N * 4);
    int* rowptr = (int*)(ws + off);    off += align256((size_t)(N + 1) * 4);
    int* cursor = (int*)(ws + off);    off += align256((size_t)N * 4);
    int* bsum = (int*)(ws + off);      off += align256((size_t)1024 * 4);
    int* ssrc = (int*)(ws + off);      off += align256((size_t)E * 4);
    short* wtl1 = (short*)(ws + off);  off += align256((size_t)256 * 64 * 2);
    short* wtr1 = (short*)(ws + off);  off += align256((size_t)256 * 64 * 2);
    short* wtl2 = (short*)(ws + off);  off += align256((size_t)256 * 256 * 2);
    short* wtr2 = (short*)(ws + off);  off += align256((size_t)256 * 256 * 2);
    (void)ws_size;

    float* outf = (float*)d_out;

    const int egrid1 = (E + 255) / 256;
    const int nblk = (N + 255) / 256;
    const int NPW = 4;
    const int ngat = (N + 4 * NPW - 1) / (4 * NPW);   // 3125 blocks

    // ---- weight transposes (bf16), one launch ----
    wtrans_all_k<<<(2 * 256 * 64 + 2 * 256 * 256 + 255) / 256, 256, 0, stream>>>(
        Wl1, Wr1, Wl2, Wr2, wtl1, wtr1, wtl2, wtr2);

    // ---- MLP encoder ----
    {
        dim3 g1((N + 63) / 64, 1);
        gemm_bias_act<<<g1, 256, 0, stream>>>(x,  W1, b1, h1, N, 64, 32, 1);
        gemm_bias_act<<<g1, 256, 0, stream>>>(h1, W2, b2, h2, N, 64, 64, 1);
    }

    // ---- GAT layer 1 transforms (bf16 MFMA): h2 -> xl, xr ----
    {
        dim3 g((N + 127) / 128, 2, 2);
        gemm_mfma_dual<<<g, 256, 0, stream>>>(h2, wtl1, bl1, xl, wtr1, br1, xr,
                                              N, 256, 64);
    }

    // ---- CSR build (h1/h2 now dead; ea_s reuses their space) ----
    hipMemsetAsync(deg, 0, (size_t)N * 4, stream);
    hist_k<<<egrid1, 256, 0, stream>>>(dst, deg, E);
    scan1_k<<<nblk, 256, 0, stream>>>(deg, rowptr, bsum, N);
    scan2_k<<<1, 256, 0, stream>>>(bsum, nblk);
    scan3_k<<<nblk, 256, 0, stream>>>(rowptr, bsum, cursor, N, E);
    scatter_k<<<egrid1, 256, 0, stream>>>(src, dst, (const float4*)eattr,
                                          cursor, ssrc, ea_s, E);

    // ---- GAT layer 1 fused edge/softmax/agg ----
    node_gat_k<4, NPW><<<ngat, 256, 0, stream>>>(xl, xr, ea_s, ssrc,
                                                 We1, att1, bias1,
                                                 rowptr, out1, N);

    // ---- GAT layer 2 transforms (bf16 MFMA): out1 -> xl, xr ----
    {
        dim3 g((N + 127) / 128, 2, 2);
        gemm_mfma_dual<<<g, 256, 0, stream>>>(out1, wtl2, bl2, xl, wtr2, br2, xr,
                                              N, 256, 256);
    }

    // ---- GAT layer 2 fused edge/softmax/agg ----
    node_gat_k<1, NPW><<<ngat, 256, 0, stream>>>(xl, xr, ea_s, ssrc,
                                                 We2, att2, bias2,
                                                 rowptr, outf, N);
}

// Round 8
// 517.335 us; speedup vs baseline: 5.1458x; 1.0321x over previous
//
#include <hip/hip_runtime.h>
#include <hip/hip_bf16.h>
#include <math.h>

#define LR_SLOPE 0.2f

typedef __attribute__((ext_vector_type(8))) short bf16x8;
typedef __attribute__((ext_vector_type(4))) float f32x4;
typedef __attribute__((ext_vector_type(2))) float f32x2;

// fp32 -> bf16 round-to-nearest-even (bit trick)
__device__ __forceinline__ unsigned short f2bf(float f) {
    unsigned u = __float_as_uint(f);
    u = (u + 0x7FFFu + ((u >> 16) & 1u)) >> 16;
    return (unsigned short)u;
}

// packed 2xfp32 helpers -> v_pk_fma_f32 / v_pk_max_f32 on CDNA
__device__ __forceinline__ f32x2 pk_fma(f32x2 a, f32x2 b, f32x2 c) {
    return __builtin_elementwise_fma(a, b, c);
}
__device__ __forceinline__ f32x2 pk_max(f32x2 a, f32x2 b) {
    return __builtin_elementwise_max(a, b);
}

// ---------- small GEMM (MLP, N=64): out = act(A@W + bias), fp32 or bf16 out ----------
__global__ __launch_bounds__(256) void gemm_bias_act(
    const float* __restrict__ A, const float* __restrict__ W,
    const float* __restrict__ bias, float* __restrict__ outf,
    short* __restrict__ outb, int M, int N, int K, int do_relu)
{
    __shared__ float As[16][64];
    __shared__ float Ws[16][64];
    const int tid = threadIdx.x;
    const int tx = tid & 15;
    const int ty = tid >> 4;
    const int row0 = blockIdx.x * 64;
    const int col0 = blockIdx.y * 64;

    float acc[4][4] = {{0.f}};

    for (int kk = 0; kk < K; kk += 16) {
        {
            const int ra = tid >> 2;
            const int ka = (tid & 3) << 2;
            float4 v = make_float4(0.f, 0.f, 0.f, 0.f);
            const int r = row0 + ra;
            if (r < M)
                v = *reinterpret_cast<const float4*>(&A[(size_t)r * K + kk + ka]);
            As[ka + 0][ra] = v.x;
            As[ka + 1][ra] = v.y;
            As[ka + 2][ra] = v.z;
            As[ka + 3][ra] = v.w;
        }
        {
            const int rw = tid >> 4;
            const int cw = (tid & 15) << 2;
            float4 v = *reinterpret_cast<const float4*>(
                &W[(size_t)(kk + rw) * N + col0 + cw]);
            *reinterpret_cast<float4*>(&Ws[rw][cw]) = v;
        }
        __syncthreads();
#pragma unroll
        for (int k = 0; k < 16; ++k) {
            const float4 a = *reinterpret_cast<const float4*>(&As[k][ty * 4]);
            const float4 b = *reinterpret_cast<const float4*>(&Ws[k][tx * 4]);
            const float av[4] = {a.x, a.y, a.z, a.w};
            const float bv[4] = {b.x, b.y, b.z, b.w};
#pragma unroll
            for (int i = 0; i < 4; ++i)
#pragma unroll
                for (int j = 0; j < 4; ++j)
                    acc[i][j] += av[i] * bv[j];
        }
        __syncthreads();
    }

    const int cbase = col0 + tx * 4;
#pragma unroll
    for (int i = 0; i < 4; ++i) {
        const int r = row0 + ty * 4 + i;
        if (r >= M) continue;
        float v[4];
#pragma unroll
        for (int j = 0; j < 4; ++j) {
            v[j] = acc[i][j] + bias[cbase + j];
            if (do_relu) v[j] = fmaxf(v[j], 0.f);
        }
        if (outb) {
            short4 s;
            s.x = (short)f2bf(v[0]); s.y = (short)f2bf(v[1]);
            s.z = (short)f2bf(v[2]); s.w = (short)f2bf(v[3]);
            *reinterpret_cast<short4*>(&outb[(size_t)r * N + cbase]) = s;
        } else {
            float4 o; o.x = v[0]; o.y = v[1]; o.z = v[2]; o.w = v[3];
            *reinterpret_cast<float4*>(&outf[(size_t)r * N + cbase]) = o;
        }
    }
}

// ---------- all 4 weight transposes + bf16 convert in one launch ----------
__global__ void wtrans_all_k(
    const float* __restrict__ Wl1, const float* __restrict__ Wr1,
    const float* __restrict__ Wl2, const float* __restrict__ Wr2,
    short* __restrict__ o1, short* __restrict__ o2,
    short* __restrict__ o3, short* __restrict__ o4)
{
    const int i = blockIdx.x * 256 + threadIdx.x;
    const int S1 = 256 * 64, S2 = 256 * 256;
    if (i < S1) {
        const int n = i / 64, k = i % 64;
        o1[i] = (short)f2bf(Wl1[(size_t)k * 256 + n]);
    } else if (i < 2 * S1) {
        const int j = i - S1;
        const int n = j / 64, k = j % 64;
        o2[j] = (short)f2bf(Wr1[(size_t)k * 256 + n]);
    } else if (i < 2 * S1 + S2) {
        const int j = i - 2 * S1;
        const int n = j / 256, k = j % 256;
        o3[j] = (short)f2bf(Wl2[(size_t)k * 256 + n]);
    } else if (i < 2 * S1 + 2 * S2) {
        const int j = i - 2 * S1 - S2;
        const int n = j / 256, k = j % 256;
        o4[j] = (short)f2bf(Wr2[(size_t)k * 256 + n]);
    }
}

// ---------- MFMA dual GEMM: {out0,out1} = A @ {W0,W1} + {b0,b1} ----------
// A: bf16 [M][K]. Wt*: bf16 [N][K] (pre-transposed).
__global__ __launch_bounds__(256) void gemm_mfma_dual(
    const short* __restrict__ A,
    const short* __restrict__ Wt0, const float* __restrict__ b0,
    float* __restrict__ out0,
    const short* __restrict__ Wt1, const float* __restrict__ b1,
    float* __restrict__ out1,
    int M, int N, int K)
{
    const short* __restrict__ Wt   = blockIdx.z ? Wt1 : Wt0;
    const float* __restrict__ bias = blockIdx.z ? b1 : b0;
    float* __restrict__ out        = blockIdx.z ? out1 : out0;

    __shared__ __align__(16) short As[4][128][8];
    __shared__ __align__(16) short Bs[4][128][8];

    const int tid = threadIdx.x;
    const int lane = tid & 63;
    const int wid = tid >> 6;
    const int wm = wid >> 1, wn = wid & 1;
    const int row0 = blockIdx.x * 128;
    const int col0 = blockIdx.y * 128;

    f32x4 acc[4][4] = {};

    const int srow = tid & 127;
    const int skg2 = tid >> 7;

    for (int kk = 0; kk < K; kk += 32) {
        {
            const int r = row0 + srow;
            bf16x8 a0 = {0, 0, 0, 0, 0, 0, 0, 0};
            bf16x8 a1 = {0, 0, 0, 0, 0, 0, 0, 0};
            if (r < M) {
                const bf16x8* p = reinterpret_cast<const bf16x8*>(
                    &A[(size_t)r * K + kk + skg2 * 16]);
                a0 = p[0]; a1 = p[1];
            }
            *reinterpret_cast<bf16x8*>(&As[skg2 * 2 + 0][srow][0]) = a0;
            *reinterpret_cast<bf16x8*>(&As[skg2 * 2 + 1][srow][0]) = a1;
        }
        {
            const float4* p = reinterpret_cast<const float4*>(
                &Wt[(size_t)(col0 + srow) * K + kk + skg2 * 16]);
            *reinterpret_cast<float4*>(&Bs[skg2 * 2 + 0][srow][0]) = p[0];
            *reinterpret_cast<float4*>(&Bs[skg2 * 2 + 1][srow][0]) = p[1];
        }
        __syncthreads();

        const int kg = lane >> 4, li = lane & 15;
        bf16x8 af[4], bfr[4];
#pragma unroll
        for (int mi = 0; mi < 4; ++mi)
            af[mi] = *reinterpret_cast<bf16x8*>(&As[kg][wm * 64 + mi * 16 + li][0]);
#pragma unroll
        for (int ni = 0; ni < 4; ++ni)
            bfr[ni] = *reinterpret_cast<bf16x8*>(&Bs[kg][wn * 64 + ni * 16 + li][0]);
#pragma unroll
        for (int mi = 0; mi < 4; ++mi)
#pragma unroll
            for (int ni = 0; ni < 4; ++ni)
                acc[mi][ni] = __builtin_amdgcn_mfma_f32_16x16x32_bf16(
                    af[mi], bfr[ni], acc[mi][ni], 0, 0, 0);
        __syncthreads();
    }

    const int li = lane & 15, lq = lane >> 4;
#pragma unroll
    for (int ni = 0; ni < 4; ++ni) {
        const int c = col0 + wn * 64 + ni * 16 + li;
        const float bv = bias[c];
#pragma unroll
        for (int mi = 0; mi < 4; ++mi) {
#pragma unroll
            for (int r = 0; r < 4; ++r) {
                const int row = row0 + wm * 64 + mi * 16 + lq * 4 + r;
                if (row < M) out[(size_t)row * N + c] = acc[mi][ni][r] + bv;
            }
        }
    }
}

// ---------- CSR build ----------
__global__ void hist_k(const int* __restrict__ dst, int* __restrict__ deg, int E)
{
    const int e = blockIdx.x * blockDim.x + threadIdx.x;
    if (e < E) atomicAdd(&deg[dst[e]], 1);
}

__global__ void scan1_k(const int* __restrict__ deg, int* __restrict__ rowptr,
                        int* __restrict__ bsum, int N)
{
    __shared__ int buf[256];
    const int i = blockIdx.x * 256 + threadIdx.x;
    const int v = (i < N) ? deg[i] : 0;
    buf[threadIdx.x] = v;
    __syncthreads();
#pragma unroll
    for (int off = 1; off < 256; off <<= 1) {
        const int t = (threadIdx.x >= (unsigned)off) ? buf[threadIdx.x - off] : 0;
        __syncthreads();
        buf[threadIdx.x] += t;
        __syncthreads();
    }
    if (i < N) rowptr[i] = buf[threadIdx.x] - v;
    if (threadIdx.x == 255) bsum[blockIdx.x] = buf[255];
}

__global__ void scan2_k(int* __restrict__ bsum, int nb)
{
    __shared__ int buf[256];
    const int v = (threadIdx.x < (unsigned)nb) ? bsum[threadIdx.x] : 0;
    buf[threadIdx.x] = v;
    __syncthreads();
#pragma unroll
    for (int off = 1; off < 256; off <<= 1) {
        const int t = (threadIdx.x >= (unsigned)off) ? buf[threadIdx.x - off] : 0;
        __syncthreads();
        buf[threadIdx.x] += t;
        __syncthreads();
    }
    if (threadIdx.x < (unsigned)nb) bsum[threadIdx.x] = buf[threadIdx.x] - v;
}

__global__ void scan3_k(int* __restrict__ rowptr, const int* __restrict__ bsum,
                        int* __restrict__ cursor, int N, int E)
{
    const int i = blockIdx.x * 256 + threadIdx.x;
    if (i < N) {
        const int r = rowptr[i] + bsum[blockIdx.x];
        rowptr[i] = r;
        cursor[i] = r;
    }
    if (i == 0) rowptr[N] = E;
}

// scatter src AND the eattr payload into dst-sorted order
__global__ void scatter_k(const int* __restrict__ src, const int* __restrict__ dst,
                          const float4* __restrict__ eattr,
                          int* __restrict__ cursor,
                          int* __restrict__ ssrc, float4* __restrict__ ea_s, int E)
{
    const int e = blockIdx.x * blockDim.x + threadIdx.x;
    if (e >= E) return;
    const int d = dst[e];
    const int p = atomicAdd(&cursor[d], 1);
    ssrc[p] = src[e];
    const float4 e0 = eattr[2 * e];
    const float4 e1 = eattr[2 * e + 1];
    ea_s[2 * p] = e0;
    ea_s[2 * p + 1] = e1;
}

// ---------- fused node-centric GATv2 (packed fp32 math) ----------
// NPW nodes per wave; We/att/bias in registers across nodes.
// Lane owns 4 contiguous channels of one head (as 2 x f32x2):
//   H=4: head = lane>>4, hc0 = head*64 + (lane&15)*4  (4-step reduce)
//   H=1: hc0 = lane*4                                  (6-step reduce)
// OB=1: store bf16, OB=0: store fp32.
template <int H, int NPW, int OB>
__global__ __launch_bounds__(256, 4) void node_gat_k(
    const float* __restrict__ xl, const float* __restrict__ xr,
    const float4* __restrict__ ea_s, const int* __restrict__ ssrc,
    const float* __restrict__ We, const float* __restrict__ att,
    const float* __restrict__ bias,
    const int* __restrict__ rowptr, void* __restrict__ outv, int N)
{
    const int lane = threadIdx.x & 63;
    const int nbase = (blockIdx.x * 4 + (threadIdx.x >> 6)) * NPW;
    if (nbase >= N) return;

    const int hc0 = (H == 4) ? (((lane >> 4) << 6) + ((lane & 15) << 2))
                             : (lane << 2);

    f32x2 we2[8][2];
#pragma unroll
    for (int t = 0; t < 8; ++t) {
        const float4 v = *reinterpret_cast<const float4*>(&We[t * 256 + hc0]);
        we2[t][0] = (f32x2){v.x, v.y};
        we2[t][1] = (f32x2){v.z, v.w};
    }
    const float4 a4 = *reinterpret_cast<const float4*>(&att[hc0]);
    const f32x2 av2[2] = {(f32x2){a4.x, a4.y}, (f32x2){a4.z, a4.w}};
    const float4 b4 = *reinterpret_cast<const float4*>(&bias[hc0]);
    const f32x2 bv2[2] = {(f32x2){b4.x, b4.y}, (f32x2){b4.z, b4.w}};

    for (int ni = 0; ni < NPW; ++ni) {
        const int n = nbase + ni;
        if (n >= N) return;
        const float4 r4 = *reinterpret_cast<const float4*>(
            &xr[(unsigned)((n << 8) + hc0)]);
        const f32x2 xrv2[2] = {(f32x2){r4.x, r4.y}, (f32x2){r4.z, r4.w}};

        f32x2 acc2[2] = {(f32x2){0.f, 0.f}, (f32x2){0.f, 0.f}};
        float m = -INFINITY, den = 0.f;

        auto load_e = [&](const int k, f32x2 (&xv)[2], float (&ea)[8]) {
            const int sv = ssrc[k];
            const float4 x4 = *reinterpret_cast<const float4*>(
                &xl[(unsigned)((sv << 8) + hc0)]);
            xv[0] = (f32x2){x4.x, x4.y};
            xv[1] = (f32x2){x4.z, x4.w};
            const float4 e0 = ea_s[2 * k];
            const float4 e1 = ea_s[2 * k + 1];
            ea[0] = e0.x; ea[1] = e0.y; ea[2] = e0.z; ea[3] = e0.w;
            ea[4] = e1.x; ea[5] = e1.y; ea[6] = e1.z; ea[7] = e1.w;
        };
        auto sc_of = [&](const f32x2 (&xv)[2], const float (&ea)[8]) -> float {
            f32x2 p2 = {0.f, 0.f};
#pragma unroll
            for (int q = 0; q < 2; ++q) {
                f32x2 s = xv[q] + xrv2[q];
#pragma unroll
                for (int t = 0; t < 8; ++t)
                    s = pk_fma((f32x2){ea[t], ea[t]}, we2[t][q], s);
                s = pk_max(s, s * LR_SLOPE);       // packed leaky relu
                p2 = pk_fma(s, av2[q], p2);
            }
            float p = p2.x + p2.y;
#pragma unroll
            for (int off = 1; off < (H == 4 ? 16 : 64); off <<= 1)
                p += __shfl_xor(p, off, 64);
            return p;
        };

        const int k0 = rowptr[n], k1 = rowptr[n + 1];
        int k = k0;
        for (; k + 4 <= k1; k += 4) {
            f32x2 x0[2], x1[2], x2[2], x3[2];
            float ea0[8], ea1[8], ea2[8], ea3[8];
            load_e(k, x0, ea0);     load_e(k + 1, x1, ea1);
            load_e(k + 2, x2, ea2); load_e(k + 3, x3, ea3);
            const float s0 = sc_of(x0, ea0);
            const float s1 = sc_of(x1, ea1);
            const float s2 = sc_of(x2, ea2);
            const float s3 = sc_of(x3, ea3);
            const float nm = fmaxf(fmaxf(m, fmaxf(s0, s1)), fmaxf(s2, s3));
            const float sc = __expf(m - nm);
            const float w0 = __expf(s0 - nm), w1 = __expf(s1 - nm);
            const float w2 = __expf(s2 - nm), w3 = __expf(s3 - nm);
            den = fmaf(den, sc, (w0 + w1) + (w2 + w3));
            const f32x2 scv = {sc, sc};
            const f32x2 w0v = {w0, w0}, w1v = {w1, w1};
            const f32x2 w2v = {w2, w2}, w3v = {w3, w3};
#pragma unroll
            for (int q = 0; q < 2; ++q)
                acc2[q] = pk_fma(acc2[q], scv,
                          pk_fma(w0v, x0[q],
                          pk_fma(w1v, x1[q],
                          pk_fma(w2v, x2[q], w3v * x3[q]))));
            m = nm;
        }
        for (; k < k1; ++k) {
            f32x2 x0[2]; float ea0[8];
            load_e(k, x0, ea0);
            const float s0 = sc_of(x0, ea0);
            const float nm = fmaxf(m, s0);
            const float sc = __expf(m - nm);
            const float w0 = __expf(s0 - nm);
            den = fmaf(den, sc, w0);
            const f32x2 scv = {sc, sc};
            const f32x2 w0v = {w0, w0};
#pragma unroll
            for (int q = 0; q < 2; ++q)
                acc2[q] = pk_fma(acc2[q], scv, w0v * x0[q]);
            m = nm;
        }

        const float inv = (den > 0.f) ? 1.f / den : 0.f;
        const f32x2 invv = {inv, inv};
        const f32x2 z2 = {0.f, 0.f};
        const f32x2 o0 = pk_max(pk_fma(acc2[0], invv, bv2[0]), z2);
        const f32x2 o1 = pk_max(pk_fma(acc2[1], invv, bv2[1]), z2);
        if (OB) {
            short4 s;
            s.x = (short)f2bf(o0.x); s.y = (short)f2bf(o0.y);
            s.z = (short)f2bf(o1.x); s.w = (short)f2bf(o1.y);
            *reinterpret_cast<short4*>(
                &((short*)outv)[(unsigned)((n << 8) + hc0)]) = s;
        } else {
            float4 o; o.x = o0.x; o.y = o0.y; o.z = o1.x; o.w = o1.y;
            *reinterpret_cast<float4*>(
                &((float*)outv)[(unsigned)((n << 8) + hc0)]) = o;
        }
    }
}

extern "C" void kernel_launch(void* const* d_in, const int* in_sizes, int n_in,
                              void* d_out, int out_size, void* d_ws, size_t ws_size,
                              hipStream_t stream)
{
    const float* x     = (const float*)d_in[0];
    const int*   eidx  = (const int*)d_in[1];
    const float* eattr = (const float*)d_in[2];
    const float* W1  = (const float*)d_in[3];
    const float* b1  = (const float*)d_in[4];
    const float* W2  = (const float*)d_in[5];
    const float* b2  = (const float*)d_in[6];
    const float* Wl1 = (const float*)d_in[7];
    const float* bl1 = (const float*)d_in[8];
    const float* Wr1 = (const float*)d_in[9];
    const float* br1 = (const float*)d_in[10];
    const float* We1 = (const float*)d_in[11];
    const float* att1 = (const float*)d_in[12];
    const float* bias1 = (const float*)d_in[13];
    const float* Wl2 = (const float*)d_in[14];
    const float* bl2 = (const float*)d_in[15];
    const float* Wr2 = (const float*)d_in[16];
    const float* br2 = (const float*)d_in[17];
    const float* We2 = (const float*)d_in[18];
    const float* att2 = (const float*)d_in[19];
    const float* bias2 = (const float*)d_in[20];

    const int N = in_sizes[0] / 32;        // 50000
    const int E = in_sizes[2] / 8;         // 800000
    const int* src = eidx;
    const int* dst = eidx + E;

    // ---- workspace layout (ea_s aliases h1+h2: both dead before CSR build) ----
    auto align256 = [](size_t v) { return (v + 255) & ~(size_t)255; };
    char* ws = (char*)d_ws;
    size_t off = 0;
    float* h1 = (float*)(ws + off);    off += align256((size_t)N * 64 * 4);
    short* h2b = (short*)(ws + off);   off += align256((size_t)N * 64 * 4);
    float4* ea_s = (float4*)h1;        // E*32B == N*128*4B exactly (25.6 MB)
    float* xl = (float*)(ws + off);    off += align256((size_t)N * 256 * 4);
    float* xr = (float*)(ws + off);    off += align256((size_t)N * 256 * 4);
    short* out1b = (short*)(ws + off); off += align256((size_t)N * 256 * 4);
    int* deg = (int*)(ws + off);       off += align256((size_t)N * 4);
    int* rowptr = (int*)(ws + off);    off += align256((size_t)(N + 1) * 4);
    int* cursor = (int*)(ws + off);    off += align256((size_t)N * 4);
    int* bsum = (int*)(ws + off);      off += align256((size_t)1024 * 4);
    int* ssrc = (int*)(ws + off);      off += align256((size_t)E * 4);
    short* wtl1 = (short*)(ws + off);  off += align256((size_t)256 * 64 * 2);
    short* wtr1 = (short*)(ws + off);  off += align256((size_t)256 * 64 * 2);
    short* wtl2 = (short*)(ws + off);  off += align256((size_t)256 * 256 * 2);
    short* wtr2 = (short*)(ws + off);  off += align256((size_t)256 * 256 * 2);
    (void)ws_size;

    float* outf = (float*)d_out;

    const int egrid1 = (E + 255) / 256;
    const int nblk = (N + 255) / 256;
    const int NPW = 4;
    const int ngat = (N + 4 * NPW - 1) / (4 * NPW);

    // ---- weight transposes (bf16), one launch ----
    wtrans_all_k<<<(2 * 256 * 64 + 2 * 256 * 256 + 255) / 256, 256, 0, stream>>>(
        Wl1, Wr1, Wl2, Wr2, wtl1, wtr1, wtl2, wtr2);

    // ---- MLP encoder (h2 written as bf16 for the MFMA consumer) ----
    {
        dim3 g1((N + 63) / 64, 1);
        gemm_bias_act<<<g1, 256, 0, stream>>>(x,  W1, b1, h1, nullptr, N, 64, 32, 1);
        gemm_bias_act<<<g1, 256, 0, stream>>>(h1, W2, b2, nullptr, h2b, N, 64, 64, 1);
    }

    // ---- GAT layer 1 transforms (bf16 MFMA): h2b -> xl, xr ----
    {
        dim3 g((N + 127) / 128, 2, 2);
        gemm_mfma_dual<<<g, 256, 0, stream>>>(h2b, wtl1, bl1, xl, wtr1, br1, xr,
                                              N, 256, 64);
    }

    // ---- CSR build (h1/h2 now dead; ea_s reuses their space) ----
    hipMemsetAsync(deg, 0, (size_t)N * 4, stream);
    hist_k<<<egrid1, 256, 0, stream>>>(dst, deg, E);
    scan1_k<<<nblk, 256, 0, stream>>>(deg, rowptr, bsum, N);
    scan2_k<<<1, 256, 0, stream>>>(bsum, nblk);
    scan3_k<<<nblk, 256, 0, stream>>>(rowptr, bsum, cursor, N, E);
    scatter_k<<<egrid1, 256, 0, stream>>>(src, dst, (const float4*)eattr,
                                          cursor, ssrc, ea_s, E);

    // ---- GAT layer 1 fused edge/softmax/agg (bf16 out) ----
    node_gat_k<4, NPW, 1><<<ngat, 256, 0, stream>>>(xl, xr, ea_s, ssrc,
                                                    We1, att1, bias1,
                                                    rowptr, out1b, N);

    // ---- GAT layer 2 transforms (bf16 MFMA): out1b -> xl, xr ----
    {
        dim3 g((N + 127) / 128, 2, 2);
        gemm_mfma_dual<<<g, 256, 0, stream>>>(out1b, wtl2, bl2, xl, wtr2, br2, xr,
                                              N, 256, 256);
    }

    // ---- GAT layer 2 fused edge/softmax/agg (fp32 out) ----
    node_gat_k<1, NPW, 0><<<ngat, 256, 0, stream>>>(xl, xr, ea_s, ssrc,
                                                    We2, att2, bias2,
                                                    rowptr, outf, N);
}

// Round 9
// 472.248 us; speedup vs baseline: 5.6371x; 1.0955x over previous
//
#include <hip/hip_runtime.h>
#include <hip/hip_bf16.h>
#include <math.h>

#define LR_SLOPE 0.2f

typedef __attribute__((ext_vector_type(8))) short bf16x8;
typedef __attribute__((ext_vector_type(4))) float f32x4;
typedef __attribute__((ext_vector_type(2))) float f32x2;

// fp32 -> bf16 round-to-nearest-even (bit trick)
__device__ __forceinline__ unsigned short f2bf(float f) {
    unsigned u = __float_as_uint(f);
    u = (u + 0x7FFFu + ((u >> 16) & 1u)) >> 16;
    return (unsigned short)u;
}

// 2 packed bf16 (one u32) -> f32x2
__device__ __forceinline__ f32x2 bf2f2(unsigned u) {
    f32x2 r;
    r.x = __uint_as_float(u << 16);
    r.y = __uint_as_float(u & 0xffff0000u);
    return r;
}

// packed 2xfp32 helpers -> v_pk_fma_f32 / v_pk_max_f32 on CDNA
__device__ __forceinline__ f32x2 pk_fma(f32x2 a, f32x2 b, f32x2 c) {
    return __builtin_elementwise_fma(a, b, c);
}
__device__ __forceinline__ f32x2 pk_max(f32x2 a, f32x2 b) {
    return __builtin_elementwise_max(a, b);
}

// ---------- small GEMM (MLP, N=64): out = act(A@W + bias), fp32 or bf16 out ----------
__global__ __launch_bounds__(256) void gemm_bias_act(
    const float* __restrict__ A, const float* __restrict__ W,
    const float* __restrict__ bias, float* __restrict__ outf,
    short* __restrict__ outb, int M, int N, int K, int do_relu)
{
    __shared__ float As[16][64];
    __shared__ float Ws[16][64];
    const int tid = threadIdx.x;
    const int tx = tid & 15;
    const int ty = tid >> 4;
    const int row0 = blockIdx.x * 64;
    const int col0 = blockIdx.y * 64;

    float acc[4][4] = {{0.f}};

    for (int kk = 0; kk < K; kk += 16) {
        {
            const int ra = tid >> 2;
            const int ka = (tid & 3) << 2;
            float4 v = make_float4(0.f, 0.f, 0.f, 0.f);
            const int r = row0 + ra;
            if (r < M)
                v = *reinterpret_cast<const float4*>(&A[(size_t)r * K + kk + ka]);
            As[ka + 0][ra] = v.x;
            As[ka + 1][ra] = v.y;
            As[ka + 2][ra] = v.z;
            As[ka + 3][ra] = v.w;
        }
        {
            const int rw = tid >> 4;
            const int cw = (tid & 15) << 2;
            float4 v = *reinterpret_cast<const float4*>(
                &W[(size_t)(kk + rw) * N + col0 + cw]);
            *reinterpret_cast<float4*>(&Ws[rw][cw]) = v;
        }
        __syncthreads();
#pragma unroll
        for (int k = 0; k < 16; ++k) {
            const float4 a = *reinterpret_cast<const float4*>(&As[k][ty * 4]);
            const float4 b = *reinterpret_cast<const float4*>(&Ws[k][tx * 4]);
            const float av[4] = {a.x, a.y, a.z, a.w};
            const float bv[4] = {b.x, b.y, b.z, b.w};
#pragma unroll
            for (int i = 0; i < 4; ++i)
#pragma unroll
                for (int j = 0; j < 4; ++j)
                    acc[i][j] += av[i] * bv[j];
        }
        __syncthreads();
    }

    const int cbase = col0 + tx * 4;
#pragma unroll
    for (int i = 0; i < 4; ++i) {
        const int r = row0 + ty * 4 + i;
        if (r >= M) continue;
        float v[4];
#pragma unroll
        for (int j = 0; j < 4; ++j) {
            v[j] = acc[i][j] + bias[cbase + j];
            if (do_relu) v[j] = fmaxf(v[j], 0.f);
        }
        if (outb) {
            short4 s;
            s.x = (short)f2bf(v[0]); s.y = (short)f2bf(v[1]);
            s.z = (short)f2bf(v[2]); s.w = (short)f2bf(v[3]);
            *reinterpret_cast<short4*>(&outb[(size_t)r * N + cbase]) = s;
        } else {
            float4 o; o.x = v[0]; o.y = v[1]; o.z = v[2]; o.w = v[3];
            *reinterpret_cast<float4*>(&outf[(size_t)r * N + cbase]) = o;
        }
    }
}

// ---------- all 4 weight transposes + bf16 convert in one launch ----------
__global__ void wtrans_all_k(
    const float* __restrict__ Wl1, const float* __restrict__ Wr1,
    const float* __restrict__ Wl2, const float* __restrict__ Wr2,
    short* __restrict__ o1, short* __restrict__ o2,
    short* __restrict__ o3, short* __restrict__ o4)
{
    const int i = blockIdx.x * 256 + threadIdx.x;
    const int S1 = 256 * 64, S2 = 256 * 256;
    if (i < S1) {
        const int n = i / 64, k = i % 64;
        o1[i] = (short)f2bf(Wl1[(size_t)k * 256 + n]);
    } else if (i < 2 * S1) {
        const int j = i - S1;
        const int n = j / 64, k = j % 64;
        o2[j] = (short)f2bf(Wr1[(size_t)k * 256 + n]);
    } else if (i < 2 * S1 + S2) {
        const int j = i - 2 * S1;
        const int n = j / 256, k = j % 256;
        o3[j] = (short)f2bf(Wl2[(size_t)k * 256 + n]);
    } else if (i < 2 * S1 + 2 * S2) {
        const int j = i - 2 * S1 - S2;
        const int n = j / 256, k = j % 256;
        o4[j] = (short)f2bf(Wr2[(size_t)k * 256 + n]);
    }
}

// ---------- MFMA dual GEMM: {out0,out1} = bf16(A @ {W0,W1} + {b0,b1}) ----------
// A: bf16 [M][K]. Wt*: bf16 [N][K] (pre-transposed). Output bf16.
__global__ __launch_bounds__(256) void gemm_mfma_dual(
    const short* __restrict__ A,
    const short* __restrict__ Wt0, const float* __restrict__ b0,
    short* __restrict__ out0,
    const short* __restrict__ Wt1, const float* __restrict__ b1,
    short* __restrict__ out1,
    int M, int N, int K)
{
    const short* __restrict__ Wt   = blockIdx.z ? Wt1 : Wt0;
    const float* __restrict__ bias = blockIdx.z ? b1 : b0;
    short* __restrict__ out        = blockIdx.z ? out1 : out0;

    __shared__ __align__(16) short As[4][128][8];
    __shared__ __align__(16) short Bs[4][128][8];

    const int tid = threadIdx.x;
    const int lane = tid & 63;
    const int wid = tid >> 6;
    const int wm = wid >> 1, wn = wid & 1;
    const int row0 = blockIdx.x * 128;
    const int col0 = blockIdx.y * 128;

    f32x4 acc[4][4] = {};

    const int srow = tid & 127;
    const int skg2 = tid >> 7;

    for (int kk = 0; kk < K; kk += 32) {
        {
            const int r = row0 + srow;
            bf16x8 a0 = {0, 0, 0, 0, 0, 0, 0, 0};
            bf16x8 a1 = {0, 0, 0, 0, 0, 0, 0, 0};
            if (r < M) {
                const bf16x8* p = reinterpret_cast<const bf16x8*>(
                    &A[(size_t)r * K + kk + skg2 * 16]);
                a0 = p[0]; a1 = p[1];
            }
            *reinterpret_cast<bf16x8*>(&As[skg2 * 2 + 0][srow][0]) = a0;
            *reinterpret_cast<bf16x8*>(&As[skg2 * 2 + 1][srow][0]) = a1;
        }
        {
            const float4* p = reinterpret_cast<const float4*>(
                &Wt[(size_t)(col0 + srow) * K + kk + skg2 * 16]);
            *reinterpret_cast<float4*>(&Bs[skg2 * 2 + 0][srow][0]) = p[0];
            *reinterpret_cast<float4*>(&Bs[skg2 * 2 + 1][srow][0]) = p[1];
        }
        __syncthreads();

        const int kg = lane >> 4, li = lane & 15;
        bf16x8 af[4], bfr[4];
#pragma unroll
        for (int mi = 0; mi < 4; ++mi)
            af[mi] = *reinterpret_cast<bf16x8*>(&As[kg][wm * 64 + mi * 16 + li][0]);
#pragma unroll
        for (int ni = 0; ni < 4; ++ni)
            bfr[ni] = *reinterpret_cast<bf16x8*>(&Bs[kg][wn * 64 + ni * 16 + li][0]);
#pragma unroll
        for (int mi = 0; mi < 4; ++mi)
#pragma unroll
            for (int ni = 0; ni < 4; ++ni)
                acc[mi][ni] = __builtin_amdgcn_mfma_f32_16x16x32_bf16(
                    af[mi], bfr[ni], acc[mi][ni], 0, 0, 0);
        __syncthreads();
    }

    const int li = lane & 15, lq = lane >> 4;
#pragma unroll
    for (int ni = 0; ni < 4; ++ni) {
        const int c = col0 + wn * 64 + ni * 16 + li;
        const float bv = bias[c];
#pragma unroll
        for (int mi = 0; mi < 4; ++mi) {
#pragma unroll
            for (int r = 0; r < 4; ++r) {
                const int row = row0 + wm * 64 + mi * 16 + lq * 4 + r;
                if (row < M)
                    out[(size_t)row * N + c] = (short)f2bf(acc[mi][ni][r] + bv);
            }
        }
    }
}

// ---------- CSR build ----------
__global__ void hist_k(const int* __restrict__ dst, int* __restrict__ deg, int E)
{
    const int e = blockIdx.x * blockDim.x + threadIdx.x;
    if (e < E) atomicAdd(&deg[dst[e]], 1);
}

__global__ void scan1_k(const int* __restrict__ deg, int* __restrict__ rowptr,
                        int* __restrict__ bsum, int N)
{
    __shared__ int buf[256];
    const int i = blockIdx.x * 256 + threadIdx.x;
    const int v = (i < N) ? deg[i] : 0;
    buf[threadIdx.x] = v;
    __syncthreads();
#pragma unroll
    for (int off = 1; off < 256; off <<= 1) {
        const int t = (threadIdx.x >= (unsigned)off) ? buf[threadIdx.x - off] : 0;
        __syncthreads();
        buf[threadIdx.x] += t;
        __syncthreads();
    }
    if (i < N) rowptr[i] = buf[threadIdx.x] - v;
    if (threadIdx.x == 255) bsum[blockIdx.x] = buf[255];
}

__global__ void scan2_k(int* __restrict__ bsum, int nb)
{
    __shared__ int buf[256];
    const int v = (threadIdx.x < (unsigned)nb) ? bsum[threadIdx.x] : 0;
    buf[threadIdx.x] = v;
    __syncthreads();
#pragma unroll
    for (int off = 1; off < 256; off <<= 1) {
        const int t = (threadIdx.x >= (unsigned)off) ? buf[threadIdx.x - off] : 0;
        __syncthreads();
        buf[threadIdx.x] += t;
        __syncthreads();
    }
    if (threadIdx.x < (unsigned)nb) bsum[threadIdx.x] = buf[threadIdx.x] - v;
}

__global__ void scan3_k(int* __restrict__ rowptr, const int* __restrict__ bsum,
                        int* __restrict__ cursor, int N, int E)
{
    const int i = blockIdx.x * 256 + threadIdx.x;
    if (i < N) {
        const int r = rowptr[i] + bsum[blockIdx.x];
        rowptr[i] = r;
        cursor[i] = r;
    }
    if (i == 0) rowptr[N] = E;
}

// scatter src AND the eattr payload into dst-sorted order
__global__ void scatter_k(const int* __restrict__ src, const int* __restrict__ dst,
                          const float4* __restrict__ eattr,
                          int* __restrict__ cursor,
                          int* __restrict__ ssrc, float4* __restrict__ ea_s, int E)
{
    const int e = blockIdx.x * blockDim.x + threadIdx.x;
    if (e >= E) return;
    const int d = dst[e];
    const int p = atomicAdd(&cursor[d], 1);
    ssrc[p] = src[e];
    const float4 e0 = eattr[2 * e];
    const float4 e1 = eattr[2 * e + 1];
    ea_s[2 * p] = e0;
    ea_s[2 * p + 1] = e1;
}

// ---------- fused node-centric GATv2 (bf16 gather + packed fp32 math) ----------
// xl/xr: bf16 [N][256]. NPW nodes per wave; We/att/bias in registers.
// Lane owns 4 contiguous channels of one head:
//   H=4: head = lane>>4, hc0 = head*64 + (lane&15)*4  (4-step reduce)
//   H=1: hc0 = lane*4                                  (6-step reduce)
// OB=1: store bf16, OB=0: store fp32.
template <int H, int NPW, int OB>
__global__ __launch_bounds__(256, 4) void node_gat_k(
    const short* __restrict__ xl, const short* __restrict__ xr,
    const float4* __restrict__ ea_s, const int* __restrict__ ssrc,
    const float* __restrict__ We, const float* __restrict__ att,
    const float* __restrict__ bias,
    const int* __restrict__ rowptr, void* __restrict__ outv, int N)
{
    const int lane = threadIdx.x & 63;
    const int nbase = (blockIdx.x * 4 + (threadIdx.x >> 6)) * NPW;
    if (nbase >= N) return;

    const int hc0 = (H == 4) ? (((lane >> 4) << 6) + ((lane & 15) << 2))
                             : (lane << 2);

    f32x2 we2[8][2];
#pragma unroll
    for (int t = 0; t < 8; ++t) {
        const float4 v = *reinterpret_cast<const float4*>(&We[t * 256 + hc0]);
        we2[t][0] = (f32x2){v.x, v.y};
        we2[t][1] = (f32x2){v.z, v.w};
    }
    const float4 a4 = *reinterpret_cast<const float4*>(&att[hc0]);
    const f32x2 av2[2] = {(f32x2){a4.x, a4.y}, (f32x2){a4.z, a4.w}};
    const float4 b4 = *reinterpret_cast<const float4*>(&bias[hc0]);
    const f32x2 bv2[2] = {(f32x2){b4.x, b4.y}, (f32x2){b4.z, b4.w}};

    for (int ni = 0; ni < NPW; ++ni) {
        const int n = nbase + ni;
        if (n >= N) return;
        const uint2 rp = *reinterpret_cast<const uint2*>(
            &xr[(unsigned)((n << 8) + hc0)]);
        const f32x2 xrv2[2] = {bf2f2(rp.x), bf2f2(rp.y)};

        f32x2 acc2[2] = {(f32x2){0.f, 0.f}, (f32x2){0.f, 0.f}};
        float m = -INFINITY, den = 0.f;

        auto load_e = [&](const int k, f32x2 (&xv)[2], float (&ea)[8]) {
            const int sv = ssrc[k];
            const uint2 xp = *reinterpret_cast<const uint2*>(
                &xl[(unsigned)((sv << 8) + hc0)]);
            xv[0] = bf2f2(xp.x);
            xv[1] = bf2f2(xp.y);
            const float4 e0 = ea_s[2 * k];
            const float4 e1 = ea_s[2 * k + 1];
            ea[0] = e0.x; ea[1] = e0.y; ea[2] = e0.z; ea[3] = e0.w;
            ea[4] = e1.x; ea[5] = e1.y; ea[6] = e1.z; ea[7] = e1.w;
        };
        auto sc_of = [&](const f32x2 (&xv)[2], const float (&ea)[8]) -> float {
            f32x2 p2 = {0.f, 0.f};
#pragma unroll
            for (int q = 0; q < 2; ++q) {
                f32x2 s = xv[q] + xrv2[q];
#pragma unroll
                for (int t = 0; t < 8; ++t)
                    s = pk_fma((f32x2){ea[t], ea[t]}, we2[t][q], s);
                s = pk_max(s, s * LR_SLOPE);       // packed leaky relu
                p2 = pk_fma(s, av2[q], p2);
            }
            float p = p2.x + p2.y;
#pragma unroll
            for (int off = 1; off < (H == 4 ? 16 : 64); off <<= 1)
                p += __shfl_xor(p, off, 64);
            return p;
        };

        const int k0 = rowptr[n], k1 = rowptr[n + 1];
        int k = k0;
        for (; k + 4 <= k1; k += 4) {
            f32x2 x0[2], x1[2], x2[2], x3[2];
            float ea0[8], ea1[8], ea2[8], ea3[8];
            load_e(k, x0, ea0);     load_e(k + 1, x1, ea1);
            load_e(k + 2, x2, ea2); load_e(k + 3, x3, ea3);
            const float s0 = sc_of(x0, ea0);
            const float s1 = sc_of(x1, ea1);
            const float s2 = sc_of(x2, ea2);
            const float s3 = sc_of(x3, ea3);
            const float nm = fmaxf(fmaxf(m, fmaxf(s0, s1)), fmaxf(s2, s3));
            const float sc = __expf(m - nm);
            const float w0 = __expf(s0 - nm), w1 = __expf(s1 - nm);
            const float w2 = __expf(s2 - nm), w3 = __expf(s3 - nm);
            den = fmaf(den, sc, (w0 + w1) + (w2 + w3));
            const f32x2 scv = {sc, sc};
            const f32x2 w0v = {w0, w0}, w1v = {w1, w1};
            const f32x2 w2v = {w2, w2}, w3v = {w3, w3};
#pragma unroll
            for (int q = 0; q < 2; ++q)
                acc2[q] = pk_fma(acc2[q], scv,
                          pk_fma(w0v, x0[q],
                          pk_fma(w1v, x1[q],
                          pk_fma(w2v, x2[q], w3v * x3[q]))));
            m = nm;
        }
        for (; k < k1; ++k) {
            f32x2 x0[2]; float ea0[8];
            load_e(k, x0, ea0);
            const float s0 = sc_of(x0, ea0);
            const float nm = fmaxf(m, s0);
            const float sc = __expf(m - nm);
            const float w0 = __expf(s0 - nm);
            den = fmaf(den, sc, w0);
            const f32x2 scv = {sc, sc};
            const f32x2 w0v = {w0, w0};
#pragma unroll
            for (int q = 0; q < 2; ++q)
                acc2[q] = pk_fma(acc2[q], scv, w0v * x0[q]);
            m = nm;
        }

        const float inv = (den > 0.f) ? 1.f / den : 0.f;
        const f32x2 invv = {inv, inv};
        const f32x2 z2 = {0.f, 0.f};
        const f32x2 o0 = pk_max(pk_fma(acc2[0], invv, bv2[0]), z2);
        const f32x2 o1 = pk_max(pk_fma(acc2[1], invv, bv2[1]), z2);
        if (OB) {
            short4 s;
            s.x = (short)f2bf(o0.x); s.y = (short)f2bf(o0.y);
            s.z = (short)f2bf(o1.x); s.w = (short)f2bf(o1.y);
            *reinterpret_cast<short4*>(
                &((short*)outv)[(unsigned)((n << 8) + hc0)]) = s;
        } else {
            float4 o; o.x = o0.x; o.y = o0.y; o.z = o1.x; o.w = o1.y;
            *reinterpret_cast<float4*>(
                &((float*)outv)[(unsigned)((n << 8) + hc0)]) = o;
        }
    }
}

extern "C" void kernel_launch(void* const* d_in, const int* in_sizes, int n_in,
                              void* d_out, int out_size, void* d_ws, size_t ws_size,
                              hipStream_t stream)
{
    const float* x     = (const float*)d_in[0];
    const int*   eidx  = (const int*)d_in[1];
    const float* eattr = (const float*)d_in[2];
    const float* W1  = (const float*)d_in[3];
    const float* b1  = (const float*)d_in[4];
    const float* W2  = (const float*)d_in[5];
    const float* b2  = (const float*)d_in[6];
    const float* Wl1 = (const float*)d_in[7];
    const float* bl1 = (const float*)d_in[8];
    const float* Wr1 = (const float*)d_in[9];
    const float* br1 = (const float*)d_in[10];
    const float* We1 = (const float*)d_in[11];
    const float* att1 = (const float*)d_in[12];
    const float* bias1 = (const float*)d_in[13];
    const float* Wl2 = (const float*)d_in[14];
    const float* bl2 = (const float*)d_in[15];
    const float* Wr2 = (const float*)d_in[16];
    const float* br2 = (const float*)d_in[17];
    const float* We2 = (const float*)d_in[18];
    const float* att2 = (const float*)d_in[19];
    const float* bias2 = (const float*)d_in[20];

    const int N = in_sizes[0] / 32;        // 50000
    const int E = in_sizes[2] / 8;         // 800000
    const int* src = eidx;
    const int* dst = eidx + E;

    // ---- workspace layout (ea_s aliases h1+h2: both dead before CSR build) ----
    auto align256 = [](size_t v) { return (v + 255) & ~(size_t)255; };
    char* ws = (char*)d_ws;
    size_t off = 0;
    float* h1 = (float*)(ws + off);    off += align256((size_t)N * 64 * 4);
    short* h2b = (short*)(ws + off);   off += align256((size_t)N * 64 * 4);
    float4* ea_s = (float4*)h1;        // E*32B == N*128*4B exactly (25.6 MB)
    short* xl = (short*)(ws + off);    off += align256((size_t)N * 256 * 2);
    short* xr = (short*)(ws + off);    off += align256((size_t)N * 256 * 2);
    short* out1b = (short*)(ws + off); off += align256((size_t)N * 256 * 2);
    int* deg = (int*)(ws + off);       off += align256((size_t)N * 4);
    int* rowptr = (int*)(ws + off);    off += align256((size_t)(N + 1) * 4);
    int* cursor = (int*)(ws + off);    off += align256((size_t)N * 4);
    int* bsum = (int*)(ws + off);      off += align256((size_t)1024 * 4);
    int* ssrc = (int*)(ws + off);      off += align256((size_t)E * 4);
    short* wtl1 = (short*)(ws + off);  off += align256((size_t)256 * 64 * 2);
    short* wtr1 = (short*)(ws + off);  off += align256((size_t)256 * 64 * 2);
    short* wtl2 = (short*)(ws + off);  off += align256((size_t)256 * 256 * 2);
    short* wtr2 = (short*)(ws + off);  off += align256((size_t)256 * 256 * 2);
    (void)ws_size;

    float* outf = (float*)d_out;

    const int egrid1 = (E + 255) / 256;
    const int nblk = (N + 255) / 256;
    const int NPW = 4;
    const int ngat = (N + 4 * NPW - 1) / (4 * NPW);

    // ---- weight transposes (bf16), one launch ----
    wtrans_all_k<<<(2 * 256 * 64 + 2 * 256 * 256 + 255) / 256, 256, 0, stream>>>(
        Wl1, Wr1, Wl2, Wr2, wtl1, wtr1, wtl2, wtr2);

    // ---- MLP encoder (h2 written as bf16 for the MFMA consumer) ----
    {
        dim3 g1((N + 63) / 64, 1);
        gemm_bias_act<<<g1, 256, 0, stream>>>(x,  W1, b1, h1, nullptr, N, 64, 32, 1);
        gemm_bias_act<<<g1, 256, 0, stream>>>(h1, W2, b2, nullptr, h2b, N, 64, 64, 1);
    }

    // ---- GAT layer 1 transforms (bf16 MFMA): h2b -> xl, xr (bf16) ----
    {
        dim3 g((N + 127) / 128, 2, 2);
        gemm_mfma_dual<<<g, 256, 0, stream>>>(h2b, wtl1, bl1, xl, wtr1, br1, xr,
                                              N, 256, 64);
    }

    // ---- CSR build (h1/h2 now dead; ea_s reuses their space) ----
    hipMemsetAsync(deg, 0, (size_t)N * 4, stream);
    hist_k<<<egrid1, 256, 0, stream>>>(dst, deg, E);
    scan1_k<<<nblk, 256, 0, stream>>>(deg, rowptr, bsum, N);
    scan2_k<<<1, 256, 0, stream>>>(bsum, nblk);
    scan3_k<<<nblk, 256, 0, stream>>>(rowptr, bsum, cursor, N, E);
    scatter_k<<<egrid1, 256, 0, stream>>>(src, dst, (const float4*)eattr,
                                          cursor, ssrc, ea_s, E);

    // ---- GAT layer 1 fused edge/softmax/agg (bf16 out) ----
    node_gat_k<4, NPW, 1><<<ngat, 256, 0, stream>>>(xl, xr, ea_s, ssrc,
                                                    We1, att1, bias1,
                                                    rowptr, out1b, N);

    // ---- GAT layer 2 transforms (bf16 MFMA): out1b -> xl, xr (bf16) ----
    {
        dim3 g((N + 127) / 128, 2, 2);
        gemm_mfma_dual<<<g, 256, 0, stream>>>(out1b, wtl2, bl2, xl, wtr2, br2, xr,
                                              N, 256, 256);
    }

    // ---- GAT layer 2 fused edge/softmax/agg (fp32 out) ----
    node_gat_k<1, NPW, 0><<<ngat, 256, 0, stream>>>(xl, xr, ea_s, ssrc,
                                                    We2, att2, bias2,
                                                    rowptr, outf, N);
}

// Round 10
// 427.697 us; speedup vs baseline: 6.2243x; 1.1042x over previous
//
#include <hip/hip_runtime.h>
#include <hip/hip_bf16.h>
#include <math.h>

#define LR_SLOPE 0.2f

typedef __attribute__((ext_vector_type(8))) short bf16x8;
typedef __attribute__((ext_vector_type(4))) float f32x4;
typedef __attribute__((ext_vector_type(2))) float f32x2;

// fp32 -> bf16 round-to-nearest-even (bit trick)
__device__ __forceinline__ unsigned short f2bf(float f) {
    unsigned u = __float_as_uint(f);
    u = (u + 0x7FFFu + ((u >> 16) & 1u)) >> 16;
    return (unsigned short)u;
}

// 2 packed bf16 (one u32) -> f32x2
__device__ __forceinline__ f32x2 bf2f2(unsigned u) {
    f32x2 r;
    r.x = __uint_as_float(u << 16);
    r.y = __uint_as_float(u & 0xffff0000u);
    return r;
}

// packed 2xfp32 helpers -> v_pk_fma_f32 / v_pk_max_f32 on CDNA
__device__ __forceinline__ f32x2 pk_fma(f32x2 a, f32x2 b, f32x2 c) {
    return __builtin_elementwise_fma(a, b, c);
}
__device__ __forceinline__ f32x2 pk_max(f32x2 a, f32x2 b) {
    return __builtin_elementwise_max(a, b);
}

// v_add_f32 with DPP row-rotate: p += rotate_within_16(p, CTRL). Pure VALU.
// CTRL: row_ror:n = 0x120 | n
template <int CTRL>
__device__ __forceinline__ float add_dpp(float v) {
    const int r = __builtin_amdgcn_update_dpp(0, __float_as_int(v),
                                              CTRL, 0xF, 0xF, true);
    return v + __int_as_float(r);
}

// ---------- small GEMM (MLP, N=64): out = act(A@W + bias), fp32 or bf16 out ----------
__global__ __launch_bounds__(256) void gemm_bias_act(
    const float* __restrict__ A, const float* __restrict__ W,
    const float* __restrict__ bias, float* __restrict__ outf,
    short* __restrict__ outb, int M, int N, int K, int do_relu)
{
    __shared__ float As[16][64];
    __shared__ float Ws[16][64];
    const int tid = threadIdx.x;
    const int tx = tid & 15;
    const int ty = tid >> 4;
    const int row0 = blockIdx.x * 64;
    const int col0 = blockIdx.y * 64;

    float acc[4][4] = {{0.f}};

    for (int kk = 0; kk < K; kk += 16) {
        {
            const int ra = tid >> 2;
            const int ka = (tid & 3) << 2;
            float4 v = make_float4(0.f, 0.f, 0.f, 0.f);
            const int r = row0 + ra;
            if (r < M)
                v = *reinterpret_cast<const float4*>(&A[(size_t)r * K + kk + ka]);
            As[ka + 0][ra] = v.x;
            As[ka + 1][ra] = v.y;
            As[ka + 2][ra] = v.z;
            As[ka + 3][ra] = v.w;
        }
        {
            const int rw = tid >> 4;
            const int cw = (tid & 15) << 2;
            float4 v = *reinterpret_cast<const float4*>(
                &W[(size_t)(kk + rw) * N + col0 + cw]);
            *reinterpret_cast<float4*>(&Ws[rw][cw]) = v;
        }
        __syncthreads();
#pragma unroll
        for (int k = 0; k < 16; ++k) {
            const float4 a = *reinterpret_cast<const float4*>(&As[k][ty * 4]);
            const float4 b = *reinterpret_cast<const float4*>(&Ws[k][tx * 4]);
            const float av[4] = {a.x, a.y, a.z, a.w};
            const float bv[4] = {b.x, b.y, b.z, b.w};
#pragma unroll
            for (int i = 0; i < 4; ++i)
#pragma unroll
                for (int j = 0; j < 4; ++j)
                    acc[i][j] += av[i] * bv[j];
        }
        __syncthreads();
    }

    const int cbase = col0 + tx * 4;
#pragma unroll
    for (int i = 0; i < 4; ++i) {
        const int r = row0 + ty * 4 + i;
        if (r >= M) continue;
        float v[4];
#pragma unroll
        for (int j = 0; j < 4; ++j) {
            v[j] = acc[i][j] + bias[cbase + j];
            if (do_relu) v[j] = fmaxf(v[j], 0.f);
        }
        if (outb) {
            short4 s;
            s.x = (short)f2bf(v[0]); s.y = (short)f2bf(v[1]);
            s.z = (short)f2bf(v[2]); s.w = (short)f2bf(v[3]);
            *reinterpret_cast<short4*>(&outb[(size_t)r * N + cbase]) = s;
        } else {
            float4 o; o.x = v[0]; o.y = v[1]; o.z = v[2]; o.w = v[3];
            *reinterpret_cast<float4*>(&outf[(size_t)r * N + cbase]) = o;
        }
    }
}

// ---------- all 4 weight transposes + bf16 convert in one launch ----------
__global__ void wtrans_all_k(
    const float* __restrict__ Wl1, const float* __restrict__ Wr1,
    const float* __restrict__ Wl2, const float* __restrict__ Wr2,
    short* __restrict__ o1, short* __restrict__ o2,
    short* __restrict__ o3, short* __restrict__ o4)
{
    const int i = blockIdx.x * 256 + threadIdx.x;
    const int S1 = 256 * 64, S2 = 256 * 256;
    if (i < S1) {
        const int n = i / 64, k = i % 64;
        o1[i] = (short)f2bf(Wl1[(size_t)k * 256 + n]);
    } else if (i < 2 * S1) {
        const int j = i - S1;
        const int n = j / 64, k = j % 64;
        o2[j] = (short)f2bf(Wr1[(size_t)k * 256 + n]);
    } else if (i < 2 * S1 + S2) {
        const int j = i - 2 * S1;
        const int n = j / 256, k = j % 256;
        o3[j] = (short)f2bf(Wl2[(size_t)k * 256 + n]);
    } else if (i < 2 * S1 + 2 * S2) {
        const int j = i - 2 * S1 - S2;
        const int n = j / 256, k = j % 256;
        o4[j] = (short)f2bf(Wr2[(size_t)k * 256 + n]);
    }
}

// ---------- MFMA dual GEMM: {out0,out1} = bf16(A @ {W0,W1} + {b0,b1}) ----------
__global__ __launch_bounds__(256) void gemm_mfma_dual(
    const short* __restrict__ A,
    const short* __restrict__ Wt0, const float* __restrict__ b0,
    short* __restrict__ out0,
    const short* __restrict__ Wt1, const float* __restrict__ b1,
    short* __restrict__ out1,
    int M, int N, int K)
{
    const short* __restrict__ Wt   = blockIdx.z ? Wt1 : Wt0;
    const float* __restrict__ bias = blockIdx.z ? b1 : b0;
    short* __restrict__ out        = blockIdx.z ? out1 : out0;

    __shared__ __align__(16) short As[4][128][8];
    __shared__ __align__(16) short Bs[4][128][8];

    const int tid = threadIdx.x;
    const int lane = tid & 63;
    const int wid = tid >> 6;
    const int wm = wid >> 1, wn = wid & 1;
    const int row0 = blockIdx.x * 128;
    const int col0 = blockIdx.y * 128;

    f32x4 acc[4][4] = {};

    const int srow = tid & 127;
    const int skg2 = tid >> 7;

    for (int kk = 0; kk < K; kk += 32) {
        {
            const int r = row0 + srow;
            bf16x8 a0 = {0, 0, 0, 0, 0, 0, 0, 0};
            bf16x8 a1 = {0, 0, 0, 0, 0, 0, 0, 0};
            if (r < M) {
                const bf16x8* p = reinterpret_cast<const bf16x8*>(
                    &A[(size_t)r * K + kk + skg2 * 16]);
                a0 = p[0]; a1 = p[1];
            }
            *reinterpret_cast<bf16x8*>(&As[skg2 * 2 + 0][srow][0]) = a0;
            *reinterpret_cast<bf16x8*>(&As[skg2 * 2 + 1][srow][0]) = a1;
        }
        {
            const float4* p = reinterpret_cast<const float4*>(
                &Wt[(size_t)(col0 + srow) * K + kk + skg2 * 16]);
            *reinterpret_cast<float4*>(&Bs[skg2 * 2 + 0][srow][0]) = p[0];
            *reinterpret_cast<float4*>(&Bs[skg2 * 2 + 1][srow][0]) = p[1];
        }
        __syncthreads();

        const int kg = lane >> 4, li = lane & 15;
        bf16x8 af[4], bfr[4];
#pragma unroll
        for (int mi = 0; mi < 4; ++mi)
            af[mi] = *reinterpret_cast<bf16x8*>(&As[kg][wm * 64 + mi * 16 + li][0]);
#pragma unroll
        for (int ni = 0; ni < 4; ++ni)
            bfr[ni] = *reinterpret_cast<bf16x8*>(&Bs[kg][wn * 64 + ni * 16 + li][0]);
#pragma unroll
        for (int mi = 0; mi < 4; ++mi)
#pragma unroll
            for (int ni = 0; ni < 4; ++ni)
                acc[mi][ni] = __builtin_amdgcn_mfma_f32_16x16x32_bf16(
                    af[mi], bfr[ni], acc[mi][ni], 0, 0, 0);
        __syncthreads();
    }

    const int li = lane & 15, lq = lane >> 4;
#pragma unroll
    for (int ni = 0; ni < 4; ++ni) {
        const int c = col0 + wn * 64 + ni * 16 + li;
        const float bv = bias[c];
#pragma unroll
        for (int mi = 0; mi < 4; ++mi) {
#pragma unroll
            for (int r = 0; r < 4; ++r) {
                const int row = row0 + wm * 64 + mi * 16 + lq * 4 + r;
                if (row < M)
                    out[(size_t)row * N + c] = (short)f2bf(acc[mi][ni][r] + bv);
            }
        }
    }
}

// ---------- CSR build ----------
__global__ void hist_k(const int* __restrict__ dst, int* __restrict__ deg, int E)
{
    const int e = blockIdx.x * blockDim.x + threadIdx.x;
    if (e < E) atomicAdd(&deg[dst[e]], 1);
}

__global__ void scan1_k(const int* __restrict__ deg, int* __restrict__ rowptr,
                        int* __restrict__ bsum, int N)
{
    __shared__ int buf[256];
    const int i = blockIdx.x * 256 + threadIdx.x;
    const int v = (i < N) ? deg[i] : 0;
    buf[threadIdx.x] = v;
    __syncthreads();
#pragma unroll
    for (int off = 1; off < 256; off <<= 1) {
        const int t = (threadIdx.x >= (unsigned)off) ? buf[threadIdx.x - off] : 0;
        __syncthreads();
        buf[threadIdx.x] += t;
        __syncthreads();
    }
    if (i < N) rowptr[i] = buf[threadIdx.x] - v;
    if (threadIdx.x == 255) bsum[blockIdx.x] = buf[255];
}

__global__ void scan2_k(int* __restrict__ bsum, int nb)
{
    __shared__ int buf[256];
    const int v = (threadIdx.x < (unsigned)nb) ? bsum[threadIdx.x] : 0;
    buf[threadIdx.x] = v;
    __syncthreads();
#pragma unroll
    for (int off = 1; off < 256; off <<= 1) {
        const int t = (threadIdx.x >= (unsigned)off) ? buf[threadIdx.x - off] : 0;
        __syncthreads();
        buf[threadIdx.x] += t;
        __syncthreads();
    }
    if (threadIdx.x < (unsigned)nb) bsum[threadIdx.x] = buf[threadIdx.x] - v;
}

__global__ void scan3_k(int* __restrict__ rowptr, const int* __restrict__ bsum,
                        int* __restrict__ cursor, int N, int E)
{
    const int i = blockIdx.x * 256 + threadIdx.x;
    if (i < N) {
        const int r = rowptr[i] + bsum[blockIdx.x];
        rowptr[i] = r;
        cursor[i] = r;
    }
    if (i == 0) rowptr[N] = E;
}

// scatter src AND the eattr payload into dst-sorted order
__global__ void scatter_k(const int* __restrict__ src, const int* __restrict__ dst,
                          const float4* __restrict__ eattr,
                          int* __restrict__ cursor,
                          int* __restrict__ ssrc, float4* __restrict__ ea_s, int E)
{
    const int e = blockIdx.x * blockDim.x + threadIdx.x;
    if (e >= E) return;
    const int d = dst[e];
    const int p = atomicAdd(&cursor[d], 1);
    ssrc[p] = src[e];
    const float4 e0 = eattr[2 * e];
    const float4 e1 = eattr[2 * e + 1];
    ea_s[2 * p] = e0;
    ea_s[2 * p + 1] = e1;
}

// ---------- fused node-centric GATv2 (scalar-uniform edge loads + DPP reduce) ----------
// xl/xr: bf16 [N][256]. NPW nodes per wave; We/att/bias in registers.
// All per-edge metadata (k, ssrc[k], ea_s[k]) is wave-uniform -> forced to
// SGPR/SMEM via readfirstlane. Only the xl row gather is per-lane VMEM.
// Lane owns 4 contiguous channels of one head:
//   H=4: head = lane>>4, hc0 = head*64 + (lane&15)*4  (DPP row reduce)
//   H=1: hc0 = lane*4                (DPP row reduce + swizzle + shfl)
// OB=1: store bf16, OB=0: store fp32.
template <int H, int NPW, int OB>
__global__ __launch_bounds__(256, 4) void node_gat_k(
    const short* __restrict__ xl, const short* __restrict__ xr,
    const float4* __restrict__ ea_s, const int* __restrict__ ssrc,
    const float* __restrict__ We, const float* __restrict__ att,
    const float* __restrict__ bias,
    const int* __restrict__ rowptr, void* __restrict__ outv, int N)
{
    const int lane = threadIdx.x & 63;
    const int nbase = (blockIdx.x * 4 + (threadIdx.x >> 6)) * NPW;
    if (nbase >= N) return;

    const int hc0 = (H == 4) ? (((lane >> 4) << 6) + ((lane & 15) << 2))
                             : (lane << 2);

    f32x2 we2[8][2];
#pragma unroll
    for (int t = 0; t < 8; ++t) {
        const float4 v = *reinterpret_cast<const float4*>(&We[t * 256 + hc0]);
        we2[t][0] = (f32x2){v.x, v.y};
        we2[t][1] = (f32x2){v.z, v.w};
    }
    const float4 a4 = *reinterpret_cast<const float4*>(&att[hc0]);
    const f32x2 av2[2] = {(f32x2){a4.x, a4.y}, (f32x2){a4.z, a4.w}};
    const float4 b4 = *reinterpret_cast<const float4*>(&bias[hc0]);
    const f32x2 bv2[2] = {(f32x2){b4.x, b4.y}, (f32x2){b4.z, b4.w}};

    for (int ni = 0; ni < NPW; ++ni) {
        const int n = nbase + ni;
        if (n >= N) return;
        const uint2 rp = *reinterpret_cast<const uint2*>(
            &xr[(unsigned)((n << 8) + hc0)]);
        const f32x2 xrv2[2] = {bf2f2(rp.x), bf2f2(rp.y)};

        f32x2 acc2[2] = {(f32x2){0.f, 0.f}, (f32x2){0.f, 0.f}};
        float m = -INFINITY, den = 0.f;

        // wave-uniform loop bounds -> scalar loop, scalar edge loads
        const int k0 = __builtin_amdgcn_readfirstlane(rowptr[n]);
        const int k1 = __builtin_amdgcn_readfirstlane(rowptr[n + 1]);

        // per-edge load: sv/ea come back uniform (SGPR), xl gather per-lane
        auto load_e = [&](const int ks, f32x2 (&xv)[2], float (&ea)[8]) {
            const int sv = ssrc[ks];                       // uniform -> s_load
            const short* xp = xl + ((unsigned)sv << 8);    // uniform base
            const uint2 xpv = *reinterpret_cast<const uint2*>(xp + hc0);
            xv[0] = bf2f2(xpv.x);
            xv[1] = bf2f2(xpv.y);
            const float4 e0 = ea_s[2 * ks];                // uniform -> s_load
            const float4 e1 = ea_s[2 * ks + 1];
            ea[0] = e0.x; ea[1] = e0.y; ea[2] = e0.z; ea[3] = e0.w;
            ea[4] = e1.x; ea[5] = e1.y; ea[6] = e1.z; ea[7] = e1.w;
        };
        auto sc_of = [&](const f32x2 (&xv)[2], const float (&ea)[8]) -> float {
            f32x2 p2 = {0.f, 0.f};
#pragma unroll
            for (int q = 0; q < 2; ++q) {
                f32x2 s = xv[q] + xrv2[q];
#pragma unroll
                for (int t = 0; t < 8; ++t)
                    s = pk_fma((f32x2){ea[t], ea[t]}, we2[t][q], s);
                s = pk_max(s, s * LR_SLOPE);       // packed leaky relu
                p2 = pk_fma(s, av2[q], p2);
            }
            float p = p2.x + p2.y;
            // 16-lane rotation reduce on the VALU (no LDS round-trips)
            p = add_dpp<0x121>(p);   // row_ror:1
            p = add_dpp<0x122>(p);   // row_ror:2
            p = add_dpp<0x124>(p);   // row_ror:4
            p = add_dpp<0x128>(p);   // row_ror:8
            if (H == 1) {
                p += __int_as_float(__builtin_amdgcn_ds_swizzle(
                         __float_as_int(p), 0x401F));      // xor 16
                p += __shfl_xor(p, 32, 64);                // xor 32
            }
            return p;
        };

        int k = k0;
        for (; k + 4 <= k1; k += 4) {
            f32x2 x0[2], x1[2], x2[2], x3[2];
            float ea0[8], ea1[8], ea2[8], ea3[8];
            load_e(k, x0, ea0);     load_e(k + 1, x1, ea1);
            load_e(k + 2, x2, ea2); load_e(k + 3, x3, ea3);
            const float s0 = sc_of(x0, ea0);
            const float s1 = sc_of(x1, ea1);
            const float s2 = sc_of(x2, ea2);
            const float s3 = sc_of(x3, ea3);
            const float nm = fmaxf(fmaxf(m, fmaxf(s0, s1)), fmaxf(s2, s3));
            const float sc = __expf(m - nm);
            const float w0 = __expf(s0 - nm), w1 = __expf(s1 - nm);
            const float w2 = __expf(s2 - nm), w3 = __expf(s3 - nm);
            den = fmaf(den, sc, (w0 + w1) + (w2 + w3));
            const f32x2 scv = {sc, sc};
            const f32x2 w0v = {w0, w0}, w1v = {w1, w1};
            const f32x2 w2v = {w2, w2}, w3v = {w3, w3};
#pragma unroll
            for (int q = 0; q < 2; ++q)
                acc2[q] = pk_fma(acc2[q], scv,
                          pk_fma(w0v, x0[q],
                          pk_fma(w1v, x1[q],
                          pk_fma(w2v, x2[q], w3v * x3[q]))));
            m = nm;
        }
        for (; k < k1; ++k) {
            f32x2 x0[2]; float ea0[8];
            load_e(k, x0, ea0);
            const float s0 = sc_of(x0, ea0);
            const float nm = fmaxf(m, s0);
            const float sc = __expf(m - nm);
            const float w0 = __expf(s0 - nm);
            den = fmaf(den, sc, w0);
            const f32x2 scv = {sc, sc};
            const f32x2 w0v = {w0, w0};
#pragma unroll
            for (int q = 0; q < 2; ++q)
                acc2[q] = pk_fma(acc2[q], scv, w0v * x0[q]);
            m = nm;
        }

        const float inv = (den > 0.f) ? 1.f / den : 0.f;
        const f32x2 invv = {inv, inv};
        const f32x2 z2 = {0.f, 0.f};
        const f32x2 o0 = pk_max(pk_fma(acc2[0], invv, bv2[0]), z2);
        const f32x2 o1 = pk_max(pk_fma(acc2[1], invv, bv2[1]), z2);
        if (OB) {
            short4 s;
            s.x = (short)f2bf(o0.x); s.y = (short)f2bf(o0.y);
            s.z = (short)f2bf(o1.x); s.w = (short)f2bf(o1.y);
            *reinterpret_cast<short4*>(
                &((short*)outv)[(unsigned)((n << 8) + hc0)]) = s;
        } else {
            float4 o; o.x = o0.x; o.y = o0.y; o.z = o1.x; o.w = o1.y;
            *reinterpret_cast<float4*>(
                &((float*)outv)[(unsigned)((n << 8) + hc0)]) = o;
        }
    }
}

extern "C" void kernel_launch(void* const* d_in, const int* in_sizes, int n_in,
                              void* d_out, int out_size, void* d_ws, size_t ws_size,
                              hipStream_t stream)
{
    const float* x     = (const float*)d_in[0];
    const int*   eidx  = (const int*)d_in[1];
    const float* eattr = (const float*)d_in[2];
    const float* W1  = (const float*)d_in[3];
    const float* b1  = (const float*)d_in[4];
    const float* W2  = (const float*)d_in[5];
    const float* b2  = (const float*)d_in[6];
    const float* Wl1 = (const float*)d_in[7];
    const float* bl1 = (const float*)d_in[8];
    const float* Wr1 = (const float*)d_in[9];
    const float* br1 = (const float*)d_in[10];
    const float* We1 = (const float*)d_in[11];
    const float* att1 = (const float*)d_in[12];
    const float* bias1 = (const float*)d_in[13];
    const float* Wl2 = (const float*)d_in[14];
    const float* bl2 = (const float*)d_in[15];
    const float* Wr2 = (const float*)d_in[16];
    const float* br2 = (const float*)d_in[17];
    const float* We2 = (const float*)d_in[18];
    const float* att2 = (const float*)d_in[19];
    const float* bias2 = (const float*)d_in[20];

    const int N = in_sizes[0] / 32;        // 50000
    const int E = in_sizes[2] / 8;         // 800000
    const int* src = eidx;
    const int* dst = eidx + E;

    // ---- workspace layout (ea_s aliases h1+h2: both dead before CSR build) ----
    auto align256 = [](size_t v) { return (v + 255) & ~(size_t)255; };
    char* ws = (char*)d_ws;
    size_t off = 0;
    float* h1 = (float*)(ws + off);    off += align256((size_t)N * 64 * 4);
    short* h2b = (short*)(ws + off);   off += align256((size_t)N * 64 * 4);
    float4* ea_s = (float4*)h1;        // E*32B == N*128*4B exactly (25.6 MB)
    short* xl = (short*)(ws + off);    off += align256((size_t)N * 256 * 2);
    short* xr = (short*)(ws + off);    off += align256((size_t)N * 256 * 2);
    short* out1b = (short*)(ws + off); off += align256((size_t)N * 256 * 2);
    int* deg = (int*)(ws + off);       off += align256((size_t)N * 4);
    int* rowptr = (int*)(ws + off);    off += align256((size_t)(N + 1) * 4);
    int* cursor = (int*)(ws + off);    off += align256((size_t)N * 4);
    int* bsum = (int*)(ws + off);      off += align256((size_t)1024 * 4);
    int* ssrc = (int*)(ws + off);      off += align256((size_t)E * 4);
    short* wtl1 = (short*)(ws + off);  off += align256((size_t)256 * 64 * 2);
    short* wtr1 = (short*)(ws + off);  off += align256((size_t)256 * 64 * 2);
    short* wtl2 = (short*)(ws + off);  off += align256((size_t)256 * 256 * 2);
    short* wtr2 = (short*)(ws + off);  off += align256((size_t)256 * 256 * 2);
    (void)ws_size;

    float* outf = (float*)d_out;

    const int egrid1 = (E + 255) / 256;
    const int nblk = (N + 255) / 256;
    const int NPW = 4;
    const int ngat = (N + 4 * NPW - 1) / (4 * NPW);

    // ---- weight transposes (bf16), one launch ----
    wtrans_all_k<<<(2 * 256 * 64 + 2 * 256 * 256 + 255) / 256, 256, 0, stream>>>(
        Wl1, Wr1, Wl2, Wr2, wtl1, wtr1, wtl2, wtr2);

    // ---- MLP encoder (h2 written as bf16 for the MFMA consumer) ----
    {
        dim3 g1((N + 63) / 64, 1);
        gemm_bias_act<<<g1, 256, 0, stream>>>(x,  W1, b1, h1, nullptr, N, 64, 32, 1);
        gemm_bias_act<<<g1, 256, 0, stream>>>(h1, W2, b2, nullptr, h2b, N, 64, 64, 1);
    }

    // ---- GAT layer 1 transforms (bf16 MFMA): h2b -> xl, xr (bf16) ----
    {
        dim3 g((N + 127) / 128, 2, 2);
        gemm_mfma_dual<<<g, 256, 0, stream>>>(h2b, wtl1, bl1, xl, wtr1, br1, xr,
                                              N, 256, 64);
    }

    // ---- CSR build (h1/h2 now dead; ea_s reuses their space) ----
    hipMemsetAsync(deg, 0, (size_t)N * 4, stream);
    hist_k<<<egrid1, 256, 0, stream>>>(dst, deg, E);
    scan1_k<<<nblk, 256, 0, stream>>>(deg, rowptr, bsum, N);
    scan2_k<<<1, 256, 0, stream>>>(bsum, nblk);
    scan3_k<<<nblk, 256, 0, stream>>>(rowptr, bsum, cursor, N, E);
    scatter_k<<<egrid1, 256, 0, stream>>>(src, dst, (const float4*)eattr,
                                          cursor, ssrc, ea_s, E);

    // ---- GAT layer 1 fused edge/softmax/agg (bf16 out) ----
    node_gat_k<4, NPW, 1><<<ngat, 256, 0, stream>>>(xl, xr, ea_s, ssrc,
                                                    We1, att1, bias1,
                                                    rowptr, out1b, N);

    // ---- GAT layer 2 transforms (bf16 MFMA): out1b -> xl, xr (bf16) ----
    {
        dim3 g((N + 127) / 128, 2, 2);
        gemm_mfma_dual<<<g, 256, 0, stream>>>(out1b, wtl2, bl2, xl, wtr2, br2, xr,
                                              N, 256, 256);
    }

    // ---- GAT layer 2 fused edge/softmax/agg (fp32 out) ----
    node_gat_k<1, NPW, 0><<<ngat, 256, 0, stream>>>(xl, xr, ea_s, ssrc,
                                                    We2, att2, bias2,
                                                    rowptr, outf, N);
}